// Round 11
// baseline (2444.505 us; speedup 1.0000x reference)
//
#include <hip/hip_runtime.h>
#include <math.h>

// Problem constants
constexpr int kS = 512, kH = 768, kNH = 12, kDH = 64, kF = 3072, kL = 12;
constexpr int kN = 50000, kE = 800000, kGH = 128;

#define CDIV(a,b) (((a)+(b)-1)/(b))

struct Ptr3 { const float* p[3]; };

typedef __attribute__((ext_vector_type(8))) short bf16x8;
typedef __attribute__((ext_vector_type(4))) float f32x4;

__device__ __forceinline__ unsigned short bf16_rne(float f) {
    unsigned int u = __float_as_uint(f);
    u += 0x7fffu + ((u >> 16) & 1u);
    return (unsigned short)(u >> 16);
}
__device__ __forceinline__ float bf16_f32(unsigned short h) {
    return __uint_as_float(((unsigned int)h) << 16);
}
__device__ __forceinline__ void split2(float f, short& hi, short& lo) {
    unsigned short h = bf16_rne(f);
    hi = (short)h;
    lo = (short)bf16_rne(f - bf16_f32(h));
}

constexpr int LDR = 72;  // LDS row: 32 hi | 32 lo | 8 pad shorts (144 B)

// ---------------- generic fill ----------------
__global__ void fill_kernel(float* p, float v, long n) {
    long i = blockIdx.x * (long)blockDim.x + threadIdx.x;
    if (i < n) p[i] = v;
}

// ---------------- GCN per-graph zero init ----------------
__global__ void gcn_zero_kernel(int* icnt, float* wsum, float* svec) {
    int i = blockIdx.x * 256 + threadIdx.x;
    if (i < kN) { icnt[i] = 0; wsum[i] = 0.f; }
    if (i < kGH) svec[i] = 0.f;
}

// ---------------- embeddings + LN (+ hi/lo emit, + maskbias fold, + feat zero) ----------------
__global__ void embed_ln_kernel(const int* ids, const int* tt, const int* mask,
                                const float* we, const float* pe, const float* te,
                                const float* g, const float* b, float* out,
                                short* oh, short* ol, float* mb, float* feat) {
    int s = blockIdx.x;
    int tid = threadIdx.x;
    __shared__ float red[256];
    if (tid == 0) mb[s] = (1.f - (float)mask[s]) * -1e4f;
    if (s == 0) { feat[tid] = 0.f; feat[tid + 256] = 0.f; feat[tid + 512] = 0.f; }
    int id = ids[s], t = tt[s];
    float vals[3]; float sum = 0.f;
    #pragma unroll
    for (int r = 0; r < 3; r++) {
        int j = tid + r * 256;
        float x = we[(long)id * kH + j] + pe[(long)s * kH + j] + te[(long)t * kH + j];
        vals[r] = x; sum += x;
    }
    red[tid] = sum; __syncthreads();
    for (int off = 128; off > 0; off >>= 1) { if (tid < off) red[tid] += red[tid + off]; __syncthreads(); }
    float mean = red[0] / kH; __syncthreads();
    float vs = 0.f;
    #pragma unroll
    for (int r = 0; r < 3; r++) { float d = vals[r] - mean; vs += d * d; }
    red[tid] = vs; __syncthreads();
    for (int off = 128; off > 0; off >>= 1) { if (tid < off) red[tid] += red[tid + off]; __syncthreads(); }
    float rstd = rsqrtf(red[0] / kH + 1e-12f);
    #pragma unroll
    for (int r = 0; r < 3; r++) {
        int j = tid + r * 256;
        float o = (vals[r] - mean) * rstd * g[j] + b[j];
        out[(long)s * kH + j] = o;
        short hi, lo; split2(o, hi, lo);
        oh[(long)s * kH + j] = hi; ol[(long)s * kH + j] = lo;
    }
}

// ---------------- batched weight transpose + split ----------------
__global__ void wtrans_all_kernel(const float* __restrict__ W, short* __restrict__ Th,
                                  short* __restrict__ Tl, int K, int N, long ostride) {
    int z = blockIdx.z;
    const float* Wm = W + (long)z * K * N;
    long moff = (long)z * ostride;
    __shared__ short th[32][33], tl[32][33];
    int n0 = blockIdx.x * 32, k0 = blockIdx.y * 32;
    int c = threadIdx.x & 31, r = threadIdx.x >> 5;
    #pragma unroll
    for (int p = 0; p < 4; p++) {
        int rr = p * 8 + r;
        float f = Wm[(long)(k0 + rr) * N + n0 + c];
        short hi, lo; split2(f, hi, lo);
        th[rr][c] = hi; tl[rr][c] = lo;
    }
    __syncthreads();
    #pragma unroll
    for (int p = 0; p < 4; p++) {
        int rr = p * 8 + r;
        Th[moff + (long)(n0 + rr) * K + k0 + c] = th[c][rr];
        Tl[moff + (long)(n0 + rr) * K + k0 + c] = tl[c][rr];
    }
}

// ---------------- V transpose: v[s][kH] (head slices) -> vt[h][d][s] ----------------
__global__ void vtrans_kernel(const short* __restrict__ vh, const short* __restrict__ vl,
                              short* __restrict__ vth, short* __restrict__ vtl) {
    __shared__ short th[32][33], tl[32][33];
    int s0 = blockIdx.x * 32;
    int h = blockIdx.y >> 1, d0 = (blockIdx.y & 1) * 32;
    int c = threadIdx.x & 31, r = threadIdx.x >> 5;
    #pragma unroll
    for (int p = 0; p < 4; p++) {
        int rr = p * 8 + r;
        th[rr][c] = vh[(long)(s0 + rr) * kH + h * kDH + d0 + c];
        tl[rr][c] = vl[(long)(s0 + rr) * kH + h * kDH + d0 + c];
    }
    __syncthreads();
    #pragma unroll
    for (int p = 0; p < 4; p++) {
        int rr = p * 8 + r;
        vth[((long)h * kDH + d0 + rr) * kS + s0 + c] = th[c][rr];
        vtl[((long)h * kDH + d0 + rr) * kS + s0 + c] = tl[c][rr];
    }
}

// ======== 64x128-tile pre-split MFMA GEMM, register-prefetch double-buffered ========
__global__ __launch_bounds__(256, 4) void gemm64_pre(
    const short* __restrict__ Ah, const short* __restrict__ Al,
    const short* __restrict__ Bth, const short* __restrict__ Btl, long wstride,
    float* __restrict__ part, int M, int Nn, int K, int S)
{
    __shared__ short As[64 * LDR], Bs[128 * LDR];  // 27648 B
    int w = blockIdx.z / S, s = blockIdx.z % S;
    const short* Bh_ = Bth + (long)w * wstride;
    const short* Bl_ = Btl + (long)w * wstride;
    int Kc = K / S, kbeg = s * Kc;
    int m0 = blockIdx.y * 64, n0 = blockIdx.x * 128;
    int tid = threadIdx.x;
    int ar = tid >> 2, aq = (tid & 3) * 8;
    const short* Agh = Ah + (long)(m0 + ar) * K + kbeg + aq;
    const short* Agl = Al + (long)(m0 + ar) * K + kbeg + aq;
    int aofs = ar * LDR + aq;
    int br = tid >> 1, bq = (tid & 1) * 16;
    const short* Bgh = Bh_ + (long)(n0 + br) * K + kbeg + bq;
    const short* Bgl = Bl_ + (long)(n0 + br) * K + kbeg + bq;
    int bofs = br * LDR + bq;
    int wid = tid >> 6, lane = tid & 63;
    int wm = (wid >> 1) * 32, wn = (wid & 1) * 64;
    int fr = lane & 15, ko = (lane >> 4) * 8;
    f32x4 acc[2][4];
    #pragma unroll
    for (int i = 0; i < 2; i++)
        #pragma unroll
        for (int j = 0; j < 4; j++) acc[i][j] = (f32x4){0.f, 0.f, 0.f, 0.f};
    int nst = Kc / 32;
    bf16x8 pa0 = *(const bf16x8*)(Agh);
    bf16x8 pa1 = *(const bf16x8*)(Agl);
    bf16x8 pb0 = *(const bf16x8*)(Bgh);
    bf16x8 pb1 = *(const bf16x8*)(Bgh + 8);
    bf16x8 pb2 = *(const bf16x8*)(Bgl);
    bf16x8 pb3 = *(const bf16x8*)(Bgl + 8);
    for (int st = 0; st < nst; ++st) {
        *(bf16x8*)&As[aofs]      = pa0;
        *(bf16x8*)&As[aofs + 32] = pa1;
        *(bf16x8*)&Bs[bofs]      = pb0;
        *(bf16x8*)&Bs[bofs + 8]  = pb1;
        *(bf16x8*)&Bs[bofs + 32] = pb2;
        *(bf16x8*)&Bs[bofs + 40] = pb3;
        if (st + 1 < nst) {
            int go = (st + 1) * 32;
            pa0 = *(const bf16x8*)(Agh + go);
            pa1 = *(const bf16x8*)(Agl + go);
            pb0 = *(const bf16x8*)(Bgh + go);
            pb1 = *(const bf16x8*)(Bgh + go + 8);
            pb2 = *(const bf16x8*)(Bgl + go);
            pb3 = *(const bf16x8*)(Bgl + go + 8);
        }
        __syncthreads();
        bf16x8 bh[4], bl[4];
        #pragma unroll
        for (int j = 0; j < 4; j++) {
            int c = (wn + j * 16 + fr) * LDR + ko;
            bh[j] = *(const bf16x8*)&Bs[c];
            bl[j] = *(const bf16x8*)&Bs[c + 32];
        }
        #pragma unroll
        for (int i = 0; i < 2; i++) {
            int r = (wm + i * 16 + fr) * LDR + ko;
            bf16x8 ah = *(const bf16x8*)&As[r];
            bf16x8 al = *(const bf16x8*)&As[r + 32];
            #pragma unroll
            for (int j = 0; j < 4; j++) {
                acc[i][j] = __builtin_amdgcn_mfma_f32_16x16x32_bf16(ah, bh[j], acc[i][j], 0, 0, 0);
                acc[i][j] = __builtin_amdgcn_mfma_f32_16x16x32_bf16(ah, bl[j], acc[i][j], 0, 0, 0);
                acc[i][j] = __builtin_amdgcn_mfma_f32_16x16x32_bf16(al, bh[j], acc[i][j], 0, 0, 0);
            }
        }
        __syncthreads();
    }
    long MN = (long)M * Nn;
    float* Pp = part + (long)(w * S + s) * MN;
    int cr = (lane >> 4) * 4;
    #pragma unroll
    for (int i = 0; i < 2; i++) {
        #pragma unroll
        for (int r = 0; r < 4; r++) {
            int gm = m0 + wm + i * 16 + cr + r;
            float* rowp = &Pp[(long)gm * Nn + n0 + wn + fr];
            #pragma unroll
            for (int j = 0; j < 4; j++) rowp[j * 16] = acc[i][j][r];
        }
    }
}

// ======== GCN GEMM: A fp32 inline-split (prefetched), B pre-split; S=1 direct ========
__global__ __launch_bounds__(256, 4) void gemm64_gcn(
    const float* __restrict__ A,
    const short* __restrict__ Bth, const short* __restrict__ Btl,
    float* __restrict__ part, int M, int Nn, int K, int S)
{
    __shared__ short As[64 * LDR], Bs[128 * LDR];
    int s = blockIdx.z;
    int Kc = K / S, kbeg = s * Kc;
    int m0 = blockIdx.y * 64, n0 = blockIdx.x * 128;
    int tid = threadIdx.x;
    int ar = tid >> 2, aqf = (tid & 3) * 8;
    int gmA = m0 + ar; if (gmA > M - 1) gmA = M - 1;
    const float* Agf = A + (long)gmA * K + kbeg + aqf;
    int aofs = ar * LDR + aqf;
    int br = tid >> 1, bq = (tid & 1) * 16;
    const short* Bgh = Bth + (long)(n0 + br) * K + kbeg + bq;
    const short* Bgl = Btl + (long)(n0 + br) * K + kbeg + bq;
    int bofs = br * LDR + bq;
    int wid = tid >> 6, lane = tid & 63;
    int wm = (wid >> 1) * 32, wn = (wid & 1) * 64;
    int fr = lane & 15, ko = (lane >> 4) * 8;
    f32x4 acc[2][4];
    #pragma unroll
    for (int i = 0; i < 2; i++)
        #pragma unroll
        for (int j = 0; j < 4; j++) acc[i][j] = (f32x4){0.f, 0.f, 0.f, 0.f};
    int nst = Kc / 32;
    float4 pf0 = *(const float4*)(Agf);
    float4 pf1 = *(const float4*)(Agf + 4);
    bf16x8 pb0 = *(const bf16x8*)(Bgh);
    bf16x8 pb1 = *(const bf16x8*)(Bgh + 8);
    bf16x8 pb2 = *(const bf16x8*)(Bgl);
    bf16x8 pb3 = *(const bf16x8*)(Bgl + 8);
    for (int st = 0; st < nst; ++st) {
        short h0, l0, h1, l1, h2, l2, h3, l3, h4, l4, h5, l5, h6, l6, h7, l7;
        split2(pf0.x, h0, l0); split2(pf0.y, h1, l1); split2(pf0.z, h2, l2); split2(pf0.w, h3, l3);
        split2(pf1.x, h4, l4); split2(pf1.y, h5, l5); split2(pf1.z, h6, l6); split2(pf1.w, h7, l7);
        *(short4*)&As[aofs]      = make_short4(h0, h1, h2, h3);
        *(short4*)&As[aofs + 4]  = make_short4(h4, h5, h6, h7);
        *(short4*)&As[aofs + 32] = make_short4(l0, l1, l2, l3);
        *(short4*)&As[aofs + 36] = make_short4(l4, l5, l6, l7);
        *(bf16x8*)&Bs[bofs]      = pb0;
        *(bf16x8*)&Bs[bofs + 8]  = pb1;
        *(bf16x8*)&Bs[bofs + 32] = pb2;
        *(bf16x8*)&Bs[bofs + 40] = pb3;
        if (st + 1 < nst) {
            int go = (st + 1) * 32;
            pf0 = *(const float4*)(Agf + go);
            pf1 = *(const float4*)(Agf + go + 4);
            pb0 = *(const bf16x8*)(Bgh + go);
            pb1 = *(const bf16x8*)(Bgh + go + 8);
            pb2 = *(const bf16x8*)(Bgl + go);
            pb3 = *(const bf16x8*)(Bgl + go + 8);
        }
        __syncthreads();
        bf16x8 bh[4], bl[4];
        #pragma unroll
        for (int j = 0; j < 4; j++) {
            int c = (wn + j * 16 + fr) * LDR + ko;
            bh[j] = *(const bf16x8*)&Bs[c];
            bl[j] = *(const bf16x8*)&Bs[c + 32];
        }
        #pragma unroll
        for (int i = 0; i < 2; i++) {
            int r = (wm + i * 16 + fr) * LDR + ko;
            bf16x8 ah = *(const bf16x8*)&As[r];
            bf16x8 al = *(const bf16x8*)&As[r + 32];
            #pragma unroll
            for (int j = 0; j < 4; j++) {
                acc[i][j] = __builtin_amdgcn_mfma_f32_16x16x32_bf16(ah, bh[j], acc[i][j], 0, 0, 0);
                acc[i][j] = __builtin_amdgcn_mfma_f32_16x16x32_bf16(ah, bl[j], acc[i][j], 0, 0, 0);
                acc[i][j] = __builtin_amdgcn_mfma_f32_16x16x32_bf16(al, bh[j], acc[i][j], 0, 0, 0);
            }
        }
        __syncthreads();
    }
    long MN = (long)M * Nn;
    float* Pp = part + (long)s * MN;
    int cr = (lane >> 4) * 4;
    #pragma unroll
    for (int i = 0; i < 2; i++) {
        #pragma unroll
        for (int r = 0; r < 4; r++) {
            int gm = m0 + wm + i * 16 + cr + r;
            if (gm >= M) continue;
            float* rowp = &Pp[(long)gm * Nn + n0 + wn + fr];
            #pragma unroll
            for (int j = 0; j < 4; j++) rowp[j * 16] = acc[i][j][r];
        }
    }
}

// ======== fused flash attention (merged PV passes): per (q-block 64, head), 2 waves ========
__global__ __launch_bounds__(128) void flash_attn_kernel(
    const short* __restrict__ qh, const short* __restrict__ ql,
    const short* __restrict__ kh, const short* __restrict__ kl,
    const short* __restrict__ vth, const short* __restrict__ vtl,
    const float* __restrict__ mb,
    short* __restrict__ ctxh, short* __restrict__ ctxl)
{
    __shared__ short Qs[2 * 64 * LDR];   // 18432 B
    __shared__ short Ks[128 * LDR];      // 18432 B (K tile or V tile)
    __shared__ short Psh[4 * 64 * 40];   // 20480 B  P hi
    __shared__ short Psl[4 * 64 * 40];   // 20480 B  P lo
    int h = blockIdx.y;
    int q0 = blockIdx.x * 64;
    int tid = threadIdx.x;               // 128
    int wid = tid >> 6, lane = tid & 63;
    int wm = wid * 32;
    int fr = lane & 15, ko = (lane >> 4) * 8;
    int cr4 = (lane >> 4) * 4;
    // ---- stage Q once
    {
        int row = tid >> 1, dseg = tid & 1;
        const short* gh_ = qh + (long)(q0 + row) * kH + h * kDH + dseg * 32;
        const short* gl_ = ql + (long)(q0 + row) * kH + h * kDH + dseg * 32;
        short* dst = &Qs[(dseg * 64 + row) * LDR];
        #pragma unroll
        for (int c = 0; c < 4; c++) {
            *(bf16x8*)&dst[c * 8]      = *(const bf16x8*)(gh_ + c * 8);
            *(bf16x8*)&dst[32 + c * 8] = *(const bf16x8*)(gl_ + c * 8);
        }
    }
    float mrun[2][4], lrun[2][4];
    f32x4 accO[2][4];
    #pragma unroll
    for (int i = 0; i < 2; i++)
        #pragma unroll
        for (int r = 0; r < 4; r++) { mrun[i][r] = -1e30f; lrun[i][r] = 0.f; }
    #pragma unroll
    for (int i = 0; i < 2; i++)
        #pragma unroll
        for (int j = 0; j < 4; j++) accO[i][j] = (f32x4){0.f, 0.f, 0.f, 0.f};

    for (int t = 0; t < 4; ++t) {
        int k0t = t * 128;
        // ---- S = Q K^T over d (2 k-steps of 32) ----
        f32x4 accS[2][8];
        #pragma unroll
        for (int i = 0; i < 2; i++)
            #pragma unroll
            for (int j = 0; j < 8; j++) accS[i][j] = (f32x4){0.f, 0.f, 0.f, 0.f};
        for (int st = 0; st < 2; ++st) {
            __syncthreads();
            {   // stage K tile
                int row = tid;
                const short* gh_ = kh + (long)(k0t + row) * kH + h * kDH + st * 32;
                const short* gl_ = kl + (long)(k0t + row) * kH + h * kDH + st * 32;
                short* dst = &Ks[row * LDR];
                #pragma unroll
                for (int c = 0; c < 4; c++) {
                    *(bf16x8*)&dst[c * 8]      = *(const bf16x8*)(gh_ + c * 8);
                    *(bf16x8*)&dst[32 + c * 8] = *(const bf16x8*)(gl_ + c * 8);
                }
            }
            __syncthreads();
            bf16x8 bh[8], bl[8];
            #pragma unroll
            for (int j = 0; j < 8; j++) {
                int c = (j * 16 + fr) * LDR + ko;
                bh[j] = *(const bf16x8*)&Ks[c];
                bl[j] = *(const bf16x8*)&Ks[c + 32];
            }
            #pragma unroll
            for (int i = 0; i < 2; i++) {
                int r = (st * 64 + wm + i * 16 + fr) * LDR + ko;
                bf16x8 ah = *(const bf16x8*)&Qs[r];
                bf16x8 al = *(const bf16x8*)&Qs[r + 32];
                #pragma unroll
                for (int j = 0; j < 8; j++) {
                    accS[i][j] = __builtin_amdgcn_mfma_f32_16x16x32_bf16(ah, bh[j], accS[i][j], 0, 0, 0);
                    accS[i][j] = __builtin_amdgcn_mfma_f32_16x16x32_bf16(ah, bl[j], accS[i][j], 0, 0, 0);
                    accS[i][j] = __builtin_amdgcn_mfma_f32_16x16x32_bf16(al, bh[j], accS[i][j], 0, 0, 0);
                }
            }
        }
        // ---- online softmax ----
        float mbv[8];
        #pragma unroll
        for (int j = 0; j < 8; j++) mbv[j] = mb[k0t + j * 16 + fr];
        #pragma unroll
        for (int i = 0; i < 2; i++) {
            #pragma unroll
            for (int r = 0; r < 4; r++) {
                float mt = -1e30f;
                #pragma unroll
                for (int j = 0; j < 8; j++) {
                    float sv = accS[i][j][r] * 0.125f + mbv[j];
                    accS[i][j][r] = sv;
                    mt = fmaxf(mt, sv);
                }
                #pragma unroll
                for (int mmask = 1; mmask < 16; mmask <<= 1)
                    mt = fmaxf(mt, __shfl_xor(mt, mmask, 64));
                float mn = fmaxf(mrun[i][r], mt);
                float sc = __expf(mrun[i][r] - mn);
                mrun[i][r] = mn;
                lrun[i][r] *= sc;
                #pragma unroll
                for (int jo = 0; jo < 4; jo++) accO[i][jo][r] *= sc;
                float lt = 0.f;
                #pragma unroll
                for (int j = 0; j < 8; j++) {
                    float p = __expf(accS[i][j][r] - mn);
                    accS[i][j][r] = p;
                    lt += p;
                }
                #pragma unroll
                for (int mmask = 1; mmask < 16; mmask <<= 1)
                    lt += __shfl_xor(lt, mmask, 64);
                lrun[i][r] += lt;
            }
        }
        // ---- write P hi AND lo to LDS (one pass) ----
        #pragma unroll
        for (int i = 0; i < 2; i++)
            #pragma unroll
            for (int j = 0; j < 8; j++)
                #pragma unroll
                for (int r = 0; r < 4; r++) {
                    int rowp = wm + i * 16 + cr4 + r;
                    int idx = (j >> 1) * 2560 + rowp * 40 + (j & 1) * 16 + fr;
                    float p = accS[i][j][r];
                    unsigned short ph = bf16_rne(p);
                    Psh[idx] = (short)ph;
                    Psl[idx] = (short)bf16_rne(p - bf16_f32(ph));
                }
        // ---- merged PV: per 32-kv step, 3 MFMA terms ----
        for (int st2 = 0; st2 < 4; ++st2) {
            __syncthreads();
            {   // stage V hi+lo: 64 d rows x 32 kv
                int row = tid >> 1, half = tid & 1;
                const short* gh_ = vth + ((long)h * kDH + row) * kS + k0t + st2 * 32 + half * 16;
                const short* gl_ = vtl + ((long)h * kDH + row) * kS + k0t + st2 * 32 + half * 16;
                short* dst = &Ks[row * LDR + half * 16];
                *(bf16x8*)&dst[0]  = *(const bf16x8*)(gh_);
                *(bf16x8*)&dst[8]  = *(const bf16x8*)(gh_ + 8);
                *(bf16x8*)&dst[32] = *(const bf16x8*)(gl_);
                *(bf16x8*)&dst[40] = *(const bf16x8*)(gl_ + 8);
            }
            __syncthreads();
            bf16x8 vh_[4], vl_[4];
            #pragma unroll
            for (int j = 0; j < 4; j++) {
                int c = (j * 16 + fr) * LDR + ko;
                vh_[j] = *(const bf16x8*)&Ks[c];
                vl_[j] = *(const bf16x8*)&Ks[c + 32];
            }
            #pragma unroll
            for (int i = 0; i < 2; i++) {
                int pidx = st2 * 2560 + (wm + i * 16 + fr) * 40 + ko;
                bf16x8 pah = *(const bf16x8*)&Psh[pidx];
                bf16x8 pal = *(const bf16x8*)&Psl[pidx];
                #pragma unroll
                for (int j = 0; j < 4; j++) {
                    accO[i][j] = __builtin_amdgcn_mfma_f32_16x16x32_bf16(pah, vh_[j], accO[i][j], 0, 0, 0);
                    accO[i][j] = __builtin_amdgcn_mfma_f32_16x16x32_bf16(pah, vl_[j], accO[i][j], 0, 0, 0);
                    accO[i][j] = __builtin_amdgcn_mfma_f32_16x16x32_bf16(pal, vh_[j], accO[i][j], 0, 0, 0);
                }
            }
        }
        __syncthreads();   // protect Ps/Ks before next tile
    }
    // ---- finalize ----
    #pragma unroll
    for (int i = 0; i < 2; i++) {
        #pragma unroll
        for (int r = 0; r < 4; r++) {
            float inv = 1.f / lrun[i][r];
            int q = q0 + wm + i * 16 + cr4 + r;
            #pragma unroll
            for (int j = 0; j < 4; j++) {
                float o = accO[i][j][r] * inv;
                int col = h * kDH + j * 16 + fr;
                short hi, lo; split2(o, hi, lo);
                ctxh[(long)q * kH + col] = hi;
                ctxl[(long)q * kH + col] = lo;
            }
        }
    }
}

// ---------------- QKV epilogue: sum partials + bias -> hi/lo shorts ----------------
__global__ void splitk_epi_qkv_kernel(const float* __restrict__ part, Ptr3 bias,
                                      short* __restrict__ qh, short* __restrict__ ql,
                                      short* __restrict__ kh, short* __restrict__ kl,
                                      short* __restrict__ vh, short* __restrict__ vl,
                                      int S) {
    const long MN = (long)kS * kH;
    int w = blockIdx.y;
    long i = ((long)blockIdx.x * blockDim.x + threadIdx.x) * 4;
    if (i >= MN) return;
    const float* P = part + (long)w * S * MN + i;
    float4 a = *(const float4*)P;
    for (int s2 = 1; s2 < S; ++s2) {
        float4 b2 = *(const float4*)(P + (long)s2 * MN);
        a.x += b2.x; a.y += b2.y; a.z += b2.z; a.w += b2.w;
    }
    const float* bw = bias.p[w];
    int n = (int)(i % kH);
    a.x += bw[n]; a.y += bw[n + 1]; a.z += bw[n + 2]; a.w += bw[n + 3];
    short* oh = (w == 0) ? qh : (w == 1) ? kh : vh;
    short* ol = (w == 0) ? ql : (w == 1) ? kl : vl;
    short h0, l0, h1, l1, h2, l2, h3, l3;
    split2(a.x, h0, l0); split2(a.y, h1, l1); split2(a.z, h2, l2); split2(a.w, h3, l3);
    *(short4*)&oh[i] = make_short4(h0, h1, h2, h3);
    *(short4*)&ol[i] = make_short4(l0, l1, l2, l3);
}

// ---------------- generic epilogue: sum partials (+bias, +act) -> hi/lo shorts ----------------
__global__ void splitk_epi_sh_kernel(const float* __restrict__ part, const float* __restrict__ bias,
                                     short* __restrict__ oh, short* __restrict__ ol,
                                     long MN, int Nn, int S, int act) {
    long i = ((long)blockIdx.x * blockDim.x + threadIdx.x) * 4;
    if (i >= MN) return;
    const float* P = part + i;
    float4 a = *(const float4*)P;
    for (int s2 = 1; s2 < S; ++s2) {
        float4 b2 = *(const float4*)(P + (long)s2 * MN);
        a.x += b2.x; a.y += b2.y; a.z += b2.z; a.w += b2.w;
    }
    if (bias) {
        int n = (int)(i % Nn);
        a.x += bias[n]; a.y += bias[n + 1]; a.z += bias[n + 2]; a.w += bias[n + 3];
    }
    if (act == 1) {
        a.x = 0.5f * a.x * (1.f + erff(a.x * 0.70710678118654752f));
        a.y = 0.5f * a.y * (1.f + erff(a.y * 0.70710678118654752f));
        a.z = 0.5f * a.z * (1.f + erff(a.z * 0.70710678118654752f));
        a.w = 0.5f * a.w * (1.f + erff(a.w * 0.70710678118654752f));
    }
    short h0, l0, h1, l1, h2, l2, h3, l3;
    split2(a.x, h0, l0); split2(a.y, h1, l1); split2(a.z, h2, l2); split2(a.w, h3, l3);
    *(short4*)&oh[i] = make_short4(h0, h1, h2, h3);
    *(short4*)&ol[i] = make_short4(l0, l1, l2, l3);
}

// ---------------- fused split-K + bias + residual + LN -> fp32 + hi/lo ----------------
__global__ void splitk_epi_ln2_kernel(const float* __restrict__ part, const float* __restrict__ bias,
                                      const float* __restrict__ res, const float* __restrict__ g,
                                      const float* __restrict__ b, float* __restrict__ out,
                                      short* __restrict__ oh, short* __restrict__ ol, int S) {
    int row = blockIdx.x; int tid = threadIdx.x;
    __shared__ float red[256];
    const long MN = (long)kS * kH;
    float vals[3]; float sum = 0.f;
    #pragma unroll
    for (int r = 0; r < 3; r++) {
        int j = tid + r * 256;
        const float* P = part + (long)row * kH + j;
        float x = res[(long)row * kH + j] + bias[j];
        for (int s2 = 0; s2 < S; ++s2) x += P[(long)s2 * MN];
        vals[r] = x; sum += x;
    }
    red[tid] = sum; __syncthreads();
    for (int off = 128; off > 0; off >>= 1) { if (tid < off) red[tid] += red[tid + off]; __syncthreads(); }
    float mean = red[0] / kH; __syncthreads();
    float vs = 0.f;
    #pragma unroll
    for (int r = 0; r < 3; r++) { float d = vals[r] - mean; vs += d * d; }
    red[tid] = vs; __syncthreads();
    for (int off = 128; off > 0; off >>= 1) { if (tid < off) red[tid] += red[tid + off]; __syncthreads(); }
    float rstd = rsqrtf(red[0] / kH + 1e-12f);
    #pragma unroll
    for (int r = 0; r < 3; r++) {
        int j = tid + r * 256;
        float o = (vals[r] - mean) * rstd * g[j] + b[j];
        out[(long)row * kH + j] = o;
        short hi, lo; split2(o, hi, lo);
        oh[(long)row * kH + j] = hi; ol[(long)row * kH + j] = lo;
    }
}

// ---------------- GCN sparse kernels ----------------
__global__ void cnt_kernel(const int* __restrict__ dst, int* __restrict__ cnt, int E) {
    int e = blockIdx.x * blockDim.x + threadIdx.x;
    if (e < E) atomicAdd(&cnt[dst[e]], 1);
}

__global__ void scan1_kernel(const int* __restrict__ cnt, int* __restrict__ offs,
                             int* __restrict__ bsum, int n) {
    __shared__ int sh[256];
    int i = blockIdx.x * 256 + threadIdx.x;
    int v = (i < n) ? cnt[i] : 0;
    sh[threadIdx.x] = v; __syncthreads();
    for (int off = 1; off < 256; off <<= 1) {
        int t = (threadIdx.x >= off) ? sh[threadIdx.x - off] : 0;
        __syncthreads();
        sh[threadIdx.x] += t;
        __syncthreads();
    }
    if (i < n) offs[i] = sh[threadIdx.x] - v;
    if (threadIdx.x == 255) bsum[blockIdx.x] = sh[255];
}

__global__ void scan2_kernel(int* bsum, int nb, int* offs, int n) {
    if (threadIdx.x == 0) {
        int run = 0;
        for (int b = 0; b < nb; b++) { int t = bsum[b]; bsum[b] = run; run += t; }
        offs[n] = run;
    }
}

__global__ void scan3_kernel(const int* __restrict__ cnt, int* __restrict__ offs,
                             const int* __restrict__ bsum, int* __restrict__ cur,
                             float* __restrict__ dinv, int n) {
    int i = blockIdx.x * 256 + threadIdx.x;
    if (i >= n) return;
    int o = offs[i] + bsum[blockIdx.x];
    offs[i] = o; cur[i] = o;
    dinv[i] = rsqrtf((float)(cnt[i] + 1));
}

__global__ void csrfill_edgew_kernel(const int* __restrict__ src, const int* __restrict__ dst,
                                     int* __restrict__ cur, int* __restrict__ csr,
                                     const float* __restrict__ dinv, float* __restrict__ wsum,
                                     int E) {
    int e = blockIdx.x * blockDim.x + threadIdx.x;
    if (e < E) {
        int s2 = src[e], d = dst[e];
        int slot = atomicAdd(&cur[d], 1);
        csr[slot] = s2;
        atomicAdd(&wsum[s2], dinv[s2] * dinv[d]);
    }
}

// gather SpMM + fused self-loop/bias/relu, 8-way ILP unroll
__global__ __launch_bounds__(256) void spmm_gather_kernel(const int* __restrict__ offs,
                                                          const int* __restrict__ csr,
                                                          const float* __restrict__ dinv,
                                                          const float* __restrict__ hw,
                                                          const float* __restrict__ b1,
                                                          float* __restrict__ hout, int n) {
    int d = blockIdx.x * 2 + (threadIdx.x >> 7);
    int j = threadIdx.x & 127;
    if (d >= n) return;
    int beg = offs[d], end = offs[d + 1];
    float a0 = 0.f, a1 = 0.f, a2 = 0.f, a3 = 0.f;
    float a4 = 0.f, a5 = 0.f, a6 = 0.f, a7 = 0.f;
    int p = beg;
    for (; p + 8 <= end; p += 8) {
        int s0 = csr[p], s1 = csr[p + 1], s2 = csr[p + 2], s3 = csr[p + 3];
        int s4 = csr[p + 4], s5 = csr[p + 5], s6 = csr[p + 6], s7 = csr[p + 7];
        a0 += dinv[s0] * hw[(long)s0 * kGH + j];
        a1 += dinv[s1] * hw[(long)s1 * kGH + j];
        a2 += dinv[s2] * hw[(long)s2 * kGH + j];
        a3 += dinv[s3] * hw[(long)s3 * kGH + j];
        a4 += dinv[s4] * hw[(long)s4 * kGH + j];
        a5 += dinv[s5] * hw[(long)s5 * kGH + j];
        a6 += dinv[s6] * hw[(long)s6 * kGH + j];
        a7 += dinv[s7] * hw[(long)s7 * kGH + j];
    }
    for (; p < end; ++p) {
        int s8 = csr[p];
        a0 += dinv[s8] * hw[(long)s8 * kGH + j];
    }
    float acc = ((a0 + a1) + (a2 + a3)) + ((a4 + a5) + (a6 + a7));
    float dd = dinv[d];
    float v = acc * dd + dd * dd * hw[(long)d * kGH + j] + b1[j];
    hout[(long)d * kGH + j] = fmaxf(v, 0.f);
}

__global__ void wreduce_kernel(const float* __restrict__ h, const float* __restrict__ w,
                               const float* __restrict__ dinv, float* __restrict__ s, int n) {
    int tid = threadIdx.x; int j = tid & 127; int half = tid >> 7;
    float acc = 0.f;
    for (int u = blockIdx.x * 2 + half; u < n; u += gridDim.x * 2) {
        float di = dinv[u];
        acc += (w[u] + di * di) * h[(long)u * kGH + j];
    }
    __shared__ float red[256];
    red[tid] = acc; __syncthreads();
    if (tid < 128) atomicAdd(&s[j], red[tid] + red[tid + 128]);
}

__global__ void gcn_final_kernel(const float* s, const float* W2, const float* b2, float* g) {
    int j2 = threadIdx.x;
    float acc = 0.f;
    for (int j = 0; j < kGH; j++) acc += s[j] * W2[(long)j * kGH + j2];
    g[j2] = acc * (1.f / (float)kN) + b2[j2];
}

// ---------------- combine head ----------------
__global__ void combine_part_kernel(const float* __restrict__ cls, const float* __restrict__ gp,
                                    const float* __restrict__ gh, const float* __restrict__ Wc,
                                    float* __restrict__ feat) {
    int i0 = blockIdx.x * 32;
    int tid = threadIdx.x;
    float a0 = 0.f, a1 = 0.f, a2 = 0.f;
    for (int r = 0; r < 32; r++) {
        int i = i0 + r;
        float x = (i < 768) ? cls[i] : (i < 896) ? gp[i - 768]
                : (i < 1664) ? cls[i - 896] : gh[i - 1664];
        const float* row = Wc + (long)i * kH;
        a0 += x * row[tid]; a1 += x * row[tid + 256]; a2 += x * row[tid + 512];
    }
    atomicAdd(&feat[tid], a0);
    atomicAdd(&feat[tid + 256], a1);
    atomicAdd(&feat[tid + 512], a2);
}

// fused: bias+relu on feat, then classifier dot
__global__ void cls_head_kernel(const float* feat, const float* bc,
                                const float* W, const float* b, float* out) {
    int tid = threadIdx.x;
    float a0 = 0.f, a1 = 0.f, a2 = 0.f;
    for (int o = tid; o < kH; o += 256) {
        float f = fmaxf(feat[o] + bc[o], 0.f);
        a0 += f * W[o * 3 + 0]; a1 += f * W[o * 3 + 1]; a2 += f * W[o * 3 + 2];
    }
    __shared__ float r0[256], r1[256], r2[256];
    r0[tid] = a0; r1[tid] = a1; r2[tid] = a2; __syncthreads();
    for (int off = 128; off > 0; off >>= 1) {
        if (tid < off) { r0[tid] += r0[tid + off]; r1[tid] += r1[tid + off]; r2[tid] += r2[tid + off]; }
        __syncthreads();
    }
    if (tid == 0) { out[0] = r0[0] + b[0]; out[1] = r1[0] + b[1]; out[2] = r2[0] + b[2]; }
}

// ---------------- launch ----------------
extern "C" void kernel_launch(void* const* d_in, const int* in_sizes, int n_in,
                              void* d_out, int out_size, void* d_ws, size_t ws_size,
                              hipStream_t stream) {
    const int*   input_ids = (const int*)d_in[0];
    const int*   attn_mask = (const int*)d_in[1];
    const int*   type_ids  = (const int*)d_in[2];
    const int*   p_edges   = (const int*)d_in[3];
    const int*   h_edges   = (const int*)d_in[4];
    const float* p_nodes   = (const float*)d_in[5];
    const float* h_nodes   = (const float*)d_in[6];
    const float* word_emb  = (const float*)d_in[7];
    const float* pos_emb   = (const float*)d_in[8];
    const float* type_emb  = (const float*)d_in[9];
    const float* eln_s     = (const float*)d_in[10];
    const float* eln_b     = (const float*)d_in[11];
    const float* Wq = (const float*)d_in[12]; const float* bq = (const float*)d_in[13];
    const float* Wk = (const float*)d_in[14]; const float* bk = (const float*)d_in[15];
    const float* Wv = (const float*)d_in[16]; const float* bv = (const float*)d_in[17];
    const float* Wo = (const float*)d_in[18]; const float* bo = (const float*)d_in[19];
    const float* l1s = (const float*)d_in[20]; const float* l1b = (const float*)d_in[21];
    const float* W1 = (const float*)d_in[22]; const float* b1 = (const float*)d_in[23];
    const float* W2 = (const float*)d_in[24]; const float* b2 = (const float*)d_in[25];
    const float* l2s = (const float*)d_in[26]; const float* l2b = (const float*)d_in[27];
    const float* gW1 = (const float*)d_in[28]; const float* gb1 = (const float*)d_in[29];
    const float* gW2 = (const float*)d_in[30]; const float* gb2 = (const float*)d_in[31];
    const float* cW  = (const float*)d_in[32]; const float* cb  = (const float*)d_in[33];
    const float* clsW = (const float*)d_in[34]; const float* clsB = (const float*)d_in[35];
    float* out = (float*)d_out;

    // ---------------- workspace layout ----------------
    float* W = (float*)d_ws;
    size_t off = 0;
    auto alloc = [&](size_t n) { float* p = W + off; off += n; return p; };
    float* h    = alloc((size_t)kS * kH);
    float* h1   = alloc((size_t)kS * kH);
    float* deg  = alloc(kN);
    float* wsum = alloc(kN);
    float* svec = alloc(kGH);
    float* gp   = alloc(kGH);
    float* ghv  = alloc(kGH);
    float* mb   = alloc(kS);
    float* feat = alloc(kH);
    float* big  = W + off;

    // BERT-phase big layout (float slots)
    float* part  = big;                                // up to 18*393216 = 7.08M floats (QKV S=6)
    short* ffn1_h = (short*)(big + 7864320);
    short* ffn1_l = ffn1_h + (size_t)1572864;
    short* sm    = (short*)(big + 11796480);
    const size_t SMN = (size_t)kS * kH;
    short* q_h = sm;            short* q_l = q_h + SMN;
    short* k_h = q_l + SMN;     short* k_l = k_h + SMN;
    short* v_h = k_l + SMN;     short* v_l = v_h + SMN;
    short* vt_h = v_l + SMN;    short* vt_l = vt_h + SMN;
    short* ctx_h = vt_l + SMN;  short* ctx_l = ctx_h + SMN;
    short* h1_h = ctx_l + SMN;  short* h1_l = h1_h + SMN;
    short* hh_h = h1_l + SMN;   short* hh_l = hh_h + SMN;

    // GCN-phase overlay on big
    float* hw1 = big;
    float* agg = big + (size_t)kN * kGH;
    int* icnt  = (int*)(big + 2 * (size_t)kN * kGH);
    int* ioffs = icnt + 50048;
    int* icur  = ioffs + 50048;
    int* ibsum = icur + 50048;
    int* icsr  = ibsum + 256;
    short* gwt_h = (short*)(icsr + kE);
    short* gwt_l = gwt_h + (size_t)kH * kGH;

    // Persistent pre-converted weight cache (beyond both overlays)
    const size_t QKV_SZ = (size_t)kH * kH;      // 589824
    const size_t FF_SZ  = (size_t)kH * kF;      // 2359296
    short* wc = (short*)(big + 15000000);
    short* qkv_h = wc;                          short* qkv_l = qkv_h + 12 * 3 * QKV_SZ;
    short* wo_h  = qkv_l + 12 * 3 * QKV_SZ;     short* wo_l  = wo_h + 12 * QKV_SZ;
    short* w1_h  = wo_l + 12 * QKV_SZ;          short* w1_l  = w1_h + 12 * FF_SZ;
    short* w2_h  = w1_l + 12 * FF_SZ;           short* w2_l  = w2_h + 12 * FF_SZ;

    const long MN_H = (long)kS * kH;   // 393216
    const long MN_F = (long)kS * kF;   // 1572864
    const int nScanBlk = CDIV(kN, 256);

    // ---------- pre-convert ALL weights once ----------
    wtrans_all_kernel<<<dim3(24, 24, 12), 256, 0, stream>>>(Wq, qkv_h,              qkv_l,              kH, kH, (long)(3 * QKV_SZ));
    wtrans_all_kernel<<<dim3(24, 24, 12), 256, 0, stream>>>(Wk, qkv_h + QKV_SZ,     qkv_l + QKV_SZ,     kH, kH, (long)(3 * QKV_SZ));
    wtrans_all_kernel<<<dim3(24, 24, 12), 256, 0, stream>>>(Wv, qkv_h + 2 * QKV_SZ, qkv_l + 2 * QKV_SZ, kH, kH, (long)(3 * QKV_SZ));
    wtrans_all_kernel<<<dim3(24, 24, 12), 256, 0, stream>>>(Wo, wo_h, wo_l, kH, kH, (long)QKV_SZ);
    wtrans_all_kernel<<<dim3(96, 24, 12), 256, 0, stream>>>(W1, w1_h, w1_l, kH, kF, (long)FF_SZ);
    wtrans_all_kernel<<<dim3(24, 96, 12), 256, 0, stream>>>(W2, w2_h, w2_l, kF, kH, (long)FF_SZ);

    // ---------- GCN on both graphs ----------
    const int* gsrc[2] = { p_edges, h_edges };
    const int* gdst[2] = { p_edges + kE, h_edges + kE };
    const float* gx[2] = { p_nodes, h_nodes };
    float* gout[2] = { gp, ghv };
    wtrans_all_kernel<<<dim3(kGH / 32, kH / 32, 1), 256, 0, stream>>>(gW1, gwt_h, gwt_l, kH, kGH, 0);
    for (int gi = 0; gi < 2; gi++) {
        gcn_zero_kernel<<<nScanBlk, 256, 0, stream>>>(icnt, wsum, svec);
        cnt_kernel<<<CDIV(kE, 256), 256, 0, stream>>>(gdst[gi], icnt, kE);
        scan1_kernel<<<nScanBlk, 256, 0, stream>>>(icnt, ioffs, ibsum, kN);
        scan2_kernel<<<1, 64, 0, stream>>>(ibsum, nScanBlk, ioffs, kN);
        scan3_kernel<<<nScanBlk, 256, 0, stream>>>(icnt, ioffs, ibsum, icur, deg, kN);
        csrfill_edgew_kernel<<<CDIV(kE, 256), 256, 0, stream>>>(
            gsrc[gi], gdst[gi], icur, icsr, deg, wsum, kE);
        gemm64_gcn<<<dim3(1, CDIV(kN, 64), 1), 256, 0, stream>>>(
            gx[gi], gwt_h, gwt_l, hw1, kN, kGH, kH, 1);
        spmm_gather_kernel<<<CDIV(kN, 2), 256, 0, stream>>>(ioffs, icsr, deg, hw1, gb1, agg, kN);
        wreduce_kernel<<<512, 256, 0, stream>>>(agg, wsum, deg, svec, kN);
        gcn_final_kernel<<<1, kGH, 0, stream>>>(svec, gW2, gb2, gout[gi]);
    }

    // ---------- BERT ----------
    embed_ln_kernel<<<kS, 256, 0, stream>>>(input_ids, type_ids, attn_mask,
                                            word_emb, pos_emb, type_emb,
                                            eln_s, eln_b, h, hh_h, hh_l, mb, feat);
    for (int l = 0; l < kL; l++) {
        const float* bq_l = bq + (size_t)l * kH;
        const float* bk_l = bk + (size_t)l * kH;
        const float* bv_l = bv + (size_t)l * kH;
        const float* bo_l = bo + (size_t)l * kH;
        const float* b1_l = b1 + (size_t)l * kF;
        const float* b2_l = b2 + (size_t)l * kH;
        const float* l1s_l = l1s + (size_t)l * kH; const float* l1b_l = l1b + (size_t)l * kH;
        const float* l2s_l = l2s + (size_t)l * kH; const float* l2b_l = l2b + (size_t)l * kH;
        const short* qkvh_l = qkv_h + (size_t)l * 3 * QKV_SZ;
        const short* qkvl_l = qkv_l + (size_t)l * 3 * QKV_SZ;
        const short* woh_l = wo_h + (size_t)l * QKV_SZ;
        const short* wol_l = wo_l + (size_t)l * QKV_SZ;
        const short* w1h_l = w1_h + (size_t)l * FF_SZ;
        const short* w1l_l = w1_l + (size_t)l * FF_SZ;
        const short* w2h_l = w2_h + (size_t)l * FF_SZ;
        const short* w2l_l = w2_l + (size_t)l * FF_SZ;

        // QKV: S=6, 3 weights -> 864 blocks, 18 partials
        gemm64_pre<<<dim3(kH / 128, kS / 64, 18), 256, 0, stream>>>(
            hh_h, hh_l, qkvh_l, qkvl_l, (long)QKV_SZ, part, kS, kH, kH, 6);
        splitk_epi_qkv_kernel<<<dim3((int)(MN_H / 4 / 256), 3), 256, 0, stream>>>(
            part, Ptr3{{bq_l, bk_l, bv_l}}, q_h, q_l, k_h, k_l, v_h, v_l, 6);
        vtrans_kernel<<<dim3(kS / 32, kNH * 2), 256, 0, stream>>>(v_h, v_l, vt_h, vt_l);
        // fused flash attention -> ctx hi/lo (96 blocks x 128 threads)
        flash_attn_kernel<<<dim3(kS / 64, kNH), 128, 0, stream>>>(
            q_h, q_l, k_h, k_l, vt_h, vt_l, mb, ctx_h, ctx_l);
        // Wo: S=8 -> 384 blocks; fused epi+bias+residual+LN
        gemm64_pre<<<dim3(kH / 128, kS / 64, 8), 256, 0, stream>>>(
            ctx_h, ctx_l, woh_l, wol_l, 0, part, kS, kH, kH, 8);
        splitk_epi_ln2_kernel<<<kS, 256, 0, stream>>>(part, bo_l, h, l1s_l, l1b_l, h1, h1_h, h1_l, 8);
        // FFN1: S=4 -> 768 blocks, gelu
        gemm64_pre<<<dim3(kF / 128, kS / 64, 4), 256, 0, stream>>>(
            h1_h, h1_l, w1h_l, w1l_l, 0, part, kS, kF, kH, 4);
        splitk_epi_sh_kernel<<<(int)(MN_F / 4 / 256), 256, 0, stream>>>(
            part, b1_l, ffn1_h, ffn1_l, MN_F, kF, 4, 1);
        // FFN2: S=8 -> 384 blocks; fused epi+bias+residual+LN
        gemm64_pre<<<dim3(kH / 128, kS / 64, 8), 256, 0, stream>>>(
            ffn1_h, ffn1_l, w2h_l, w2l_l, 0, part, kS, kH, kF, 8);
        splitk_epi_ln2_kernel<<<kS, 256, 0, stream>>>(part, b2_l, h1, l2s_l, l2b_l, h, hh_h, hh_l, 8);
    }

    // ---------- combine + classifier ----------
    combine_part_kernel<<<56, 256, 0, stream>>>(h, gp, ghv, cW, feat);
    cls_head_kernel<<<1, 256, 0, stream>>>(feat, cb, clsW, clsB, out);
}

// Round 12
// 2407.874 us; speedup vs baseline: 1.0152x; 1.0152x over previous
//
#include <hip/hip_runtime.h>
#include <math.h>

// Problem constants
constexpr int kS = 512, kH = 768, kNH = 12, kDH = 64, kF = 3072, kL = 12;
constexpr int kN = 50000, kE = 800000, kGH = 128;

#define CDIV(a,b) (((a)+(b)-1)/(b))

struct Ptr3 { const float* p[3]; };

typedef __attribute__((ext_vector_type(8))) short bf16x8;
typedef __attribute__((ext_vector_type(4))) float f32x4;

__device__ __forceinline__ unsigned short bf16_rne(float f) {
    unsigned int u = __float_as_uint(f);
    u += 0x7fffu + ((u >> 16) & 1u);
    return (unsigned short)(u >> 16);
}
__device__ __forceinline__ float bf16_f32(unsigned short h) {
    return __uint_as_float(((unsigned int)h) << 16);
}
__device__ __forceinline__ void split2(float f, short& hi, short& lo) {
    unsigned short h = bf16_rne(f);
    hi = (short)h;
    lo = (short)bf16_rne(f - bf16_f32(h));
}

constexpr int LDR = 72;  // LDS row: 32 hi | 32 lo | 8 pad shorts (144 B)

// ---------------- generic fill ----------------
__global__ void fill_kernel(float* p, float v, long n) {
    long i = blockIdx.x * (long)blockDim.x + threadIdx.x;
    if (i < n) p[i] = v;
}

// ---------------- GCN per-graph zero init ----------------
__global__ void gcn_zero_kernel(int* icnt, float* wsum, float* svec) {
    int i = blockIdx.x * 256 + threadIdx.x;
    if (i < kN) { icnt[i] = 0; wsum[i] = 0.f; }
    if (i < kGH) svec[i] = 0.f;
}

// ---------------- embeddings + LN (+ hi/lo emit, + maskbias fold, + feat zero) ----------------
__global__ void embed_ln_kernel(const int* ids, const int* tt, const int* mask,
                                const float* we, const float* pe, const float* te,
                                const float* g, const float* b, float* out,
                                short* oh, short* ol, float* mb, float* feat) {
    int s = blockIdx.x;
    int tid = threadIdx.x;
    __shared__ float red[256];
    if (tid == 0) mb[s] = (1.f - (float)mask[s]) * -1e4f;
    if (s == 0) { feat[tid] = 0.f; feat[tid + 256] = 0.f; feat[tid + 512] = 0.f; }
    int id = ids[s], t = tt[s];
    float vals[3]; float sum = 0.f;
    #pragma unroll
    for (int r = 0; r < 3; r++) {
        int j = tid + r * 256;
        float x = we[(long)id * kH + j] + pe[(long)s * kH + j] + te[(long)t * kH + j];
        vals[r] = x; sum += x;
    }
    red[tid] = sum; __syncthreads();
    for (int off = 128; off > 0; off >>= 1) { if (tid < off) red[tid] += red[tid + off]; __syncthreads(); }
    float mean = red[0] / kH; __syncthreads();
    float vs = 0.f;
    #pragma unroll
    for (int r = 0; r < 3; r++) { float d = vals[r] - mean; vs += d * d; }
    red[tid] = vs; __syncthreads();
    for (int off = 128; off > 0; off >>= 1) { if (tid < off) red[tid] += red[tid + off]; __syncthreads(); }
    float rstd = rsqrtf(red[0] / kH + 1e-12f);
    #pragma unroll
    for (int r = 0; r < 3; r++) {
        int j = tid + r * 256;
        float o = (vals[r] - mean) * rstd * g[j] + b[j];
        out[(long)s * kH + j] = o;
        short hi, lo; split2(o, hi, lo);
        oh[(long)s * kH + j] = hi; ol[(long)s * kH + j] = lo;
    }
}

// ---------------- batched weight transpose + split ----------------
__global__ void wtrans_all_kernel(const float* __restrict__ W, short* __restrict__ Th,
                                  short* __restrict__ Tl, int K, int N, long ostride) {
    int z = blockIdx.z;
    const float* Wm = W + (long)z * K * N;
    long moff = (long)z * ostride;
    __shared__ short th[32][33], tl[32][33];
    int n0 = blockIdx.x * 32, k0 = blockIdx.y * 32;
    int c = threadIdx.x & 31, r = threadIdx.x >> 5;
    #pragma unroll
    for (int p = 0; p < 4; p++) {
        int rr = p * 8 + r;
        float f = Wm[(long)(k0 + rr) * N + n0 + c];
        short hi, lo; split2(f, hi, lo);
        th[rr][c] = hi; tl[rr][c] = lo;
    }
    __syncthreads();
    #pragma unroll
    for (int p = 0; p < 4; p++) {
        int rr = p * 8 + r;
        Th[moff + (long)(n0 + rr) * K + k0 + c] = th[c][rr];
        Tl[moff + (long)(n0 + rr) * K + k0 + c] = tl[c][rr];
    }
}

// ---------------- V transpose: v[s][kH] (head slices) -> vt[h][d][s] ----------------
__global__ void vtrans_kernel(const short* __restrict__ vh, const short* __restrict__ vl,
                              short* __restrict__ vth, short* __restrict__ vtl) {
    __shared__ short th[32][33], tl[32][33];
    int s0 = blockIdx.x * 32;
    int h = blockIdx.y >> 1, d0 = (blockIdx.y & 1) * 32;
    int c = threadIdx.x & 31, r = threadIdx.x >> 5;
    #pragma unroll
    for (int p = 0; p < 4; p++) {
        int rr = p * 8 + r;
        th[rr][c] = vh[(long)(s0 + rr) * kH + h * kDH + d0 + c];
        tl[rr][c] = vl[(long)(s0 + rr) * kH + h * kDH + d0 + c];
    }
    __syncthreads();
    #pragma unroll
    for (int p = 0; p < 4; p++) {
        int rr = p * 8 + r;
        vth[((long)h * kDH + d0 + rr) * kS + s0 + c] = th[c][rr];
        vtl[((long)h * kDH + d0 + rr) * kS + s0 + c] = tl[c][rr];
    }
}

// ======== 64x128-tile pre-split MFMA GEMM, register-prefetch double-buffered ========
__global__ __launch_bounds__(256, 4) void gemm64_pre(
    const short* __restrict__ Ah, const short* __restrict__ Al,
    const short* __restrict__ Bth, const short* __restrict__ Btl, long wstride,
    float* __restrict__ part, int M, int Nn, int K, int S)
{
    __shared__ short As[64 * LDR], Bs[128 * LDR];  // 27648 B
    int w = blockIdx.z / S, s = blockIdx.z % S;
    const short* Bh_ = Bth + (long)w * wstride;
    const short* Bl_ = Btl + (long)w * wstride;
    int Kc = K / S, kbeg = s * Kc;
    int m0 = blockIdx.y * 64, n0 = blockIdx.x * 128;
    int tid = threadIdx.x;
    int ar = tid >> 2, aq = (tid & 3) * 8;
    const short* Agh = Ah + (long)(m0 + ar) * K + kbeg + aq;
    const short* Agl = Al + (long)(m0 + ar) * K + kbeg + aq;
    int aofs = ar * LDR + aq;
    int br = tid >> 1, bq = (tid & 1) * 16;
    const short* Bgh = Bh_ + (long)(n0 + br) * K + kbeg + bq;
    const short* Bgl = Bl_ + (long)(n0 + br) * K + kbeg + bq;
    int bofs = br * LDR + bq;
    int wid = tid >> 6, lane = tid & 63;
    int wm = (wid >> 1) * 32, wn = (wid & 1) * 64;
    int fr = lane & 15, ko = (lane >> 4) * 8;
    f32x4 acc[2][4];
    #pragma unroll
    for (int i = 0; i < 2; i++)
        #pragma unroll
        for (int j = 0; j < 4; j++) acc[i][j] = (f32x4){0.f, 0.f, 0.f, 0.f};
    int nst = Kc / 32;
    bf16x8 pa0 = *(const bf16x8*)(Agh);
    bf16x8 pa1 = *(const bf16x8*)(Agl);
    bf16x8 pb0 = *(const bf16x8*)(Bgh);
    bf16x8 pb1 = *(const bf16x8*)(Bgh + 8);
    bf16x8 pb2 = *(const bf16x8*)(Bgl);
    bf16x8 pb3 = *(const bf16x8*)(Bgl + 8);
    for (int st = 0; st < nst; ++st) {
        *(bf16x8*)&As[aofs]      = pa0;
        *(bf16x8*)&As[aofs + 32] = pa1;
        *(bf16x8*)&Bs[bofs]      = pb0;
        *(bf16x8*)&Bs[bofs + 8]  = pb1;
        *(bf16x8*)&Bs[bofs + 32] = pb2;
        *(bf16x8*)&Bs[bofs + 40] = pb3;
        if (st + 1 < nst) {
            int go = (st + 1) * 32;
            pa0 = *(const bf16x8*)(Agh + go);
            pa1 = *(const bf16x8*)(Agl + go);
            pb0 = *(const bf16x8*)(Bgh + go);
            pb1 = *(const bf16x8*)(Bgh + go + 8);
            pb2 = *(const bf16x8*)(Bgl + go);
            pb3 = *(const bf16x8*)(Bgl + go + 8);
        }
        __syncthreads();
        bf16x8 bh[4], bl[4];
        #pragma unroll
        for (int j = 0; j < 4; j++) {
            int c = (wn + j * 16 + fr) * LDR + ko;
            bh[j] = *(const bf16x8*)&Bs[c];
            bl[j] = *(const bf16x8*)&Bs[c + 32];
        }
        #pragma unroll
        for (int i = 0; i < 2; i++) {
            int r = (wm + i * 16 + fr) * LDR + ko;
            bf16x8 ah = *(const bf16x8*)&As[r];
            bf16x8 al = *(const bf16x8*)&As[r + 32];
            #pragma unroll
            for (int j = 0; j < 4; j++) {
                acc[i][j] = __builtin_amdgcn_mfma_f32_16x16x32_bf16(ah, bh[j], acc[i][j], 0, 0, 0);
                acc[i][j] = __builtin_amdgcn_mfma_f32_16x16x32_bf16(ah, bl[j], acc[i][j], 0, 0, 0);
                acc[i][j] = __builtin_amdgcn_mfma_f32_16x16x32_bf16(al, bh[j], acc[i][j], 0, 0, 0);
            }
        }
        __syncthreads();
    }
    long MN = (long)M * Nn;
    float* Pp = part + (long)(w * S + s) * MN;
    int cr = (lane >> 4) * 4;
    #pragma unroll
    for (int i = 0; i < 2; i++) {
        #pragma unroll
        for (int r = 0; r < 4; r++) {
            int gm = m0 + wm + i * 16 + cr + r;
            float* rowp = &Pp[(long)gm * Nn + n0 + wn + fr];
            #pragma unroll
            for (int j = 0; j < 4; j++) rowp[j * 16] = acc[i][j][r];
        }
    }
}

// ======== GCN GEMM: A fp32 inline-split (prefetched), B pre-split; S=1 direct ========
__global__ __launch_bounds__(256, 4) void gemm64_gcn(
    const float* __restrict__ A,
    const short* __restrict__ Bth, const short* __restrict__ Btl,
    float* __restrict__ part, int M, int Nn, int K, int S)
{
    __shared__ short As[64 * LDR], Bs[128 * LDR];
    int s = blockIdx.z;
    int Kc = K / S, kbeg = s * Kc;
    int m0 = blockIdx.y * 64, n0 = blockIdx.x * 128;
    int tid = threadIdx.x;
    int ar = tid >> 2, aqf = (tid & 3) * 8;
    int gmA = m0 + ar; if (gmA > M - 1) gmA = M - 1;
    const float* Agf = A + (long)gmA * K + kbeg + aqf;
    int aofs = ar * LDR + aqf;
    int br = tid >> 1, bq = (tid & 1) * 16;
    const short* Bgh = Bth + (long)(n0 + br) * K + kbeg + bq;
    const short* Bgl = Btl + (long)(n0 + br) * K + kbeg + bq;
    int bofs = br * LDR + bq;
    int wid = tid >> 6, lane = tid & 63;
    int wm = (wid >> 1) * 32, wn = (wid & 1) * 64;
    int fr = lane & 15, ko = (lane >> 4) * 8;
    f32x4 acc[2][4];
    #pragma unroll
    for (int i = 0; i < 2; i++)
        #pragma unroll
        for (int j = 0; j < 4; j++) acc[i][j] = (f32x4){0.f, 0.f, 0.f, 0.f};
    int nst = Kc / 32;
    float4 pf0 = *(const float4*)(Agf);
    float4 pf1 = *(const float4*)(Agf + 4);
    bf16x8 pb0 = *(const bf16x8*)(Bgh);
    bf16x8 pb1 = *(const bf16x8*)(Bgh + 8);
    bf16x8 pb2 = *(const bf16x8*)(Bgl);
    bf16x8 pb3 = *(const bf16x8*)(Bgl + 8);
    for (int st = 0; st < nst; ++st) {
        short h0, l0, h1, l1, h2, l2, h3, l3, h4, l4, h5, l5, h6, l6, h7, l7;
        split2(pf0.x, h0, l0); split2(pf0.y, h1, l1); split2(pf0.z, h2, l2); split2(pf0.w, h3, l3);
        split2(pf1.x, h4, l4); split2(pf1.y, h5, l5); split2(pf1.z, h6, l6); split2(pf1.w, h7, l7);
        *(short4*)&As[aofs]      = make_short4(h0, h1, h2, h3);
        *(short4*)&As[aofs + 4]  = make_short4(h4, h5, h6, h7);
        *(short4*)&As[aofs + 32] = make_short4(l0, l1, l2, l3);
        *(short4*)&As[aofs + 36] = make_short4(l4, l5, l6, l7);
        *(bf16x8*)&Bs[bofs]      = pb0;
        *(bf16x8*)&Bs[bofs + 8]  = pb1;
        *(bf16x8*)&Bs[bofs + 32] = pb2;
        *(bf16x8*)&Bs[bofs + 40] = pb3;
        if (st + 1 < nst) {
            int go = (st + 1) * 32;
            pf0 = *(const float4*)(Agf + go);
            pf1 = *(const float4*)(Agf + go + 4);
            pb0 = *(const bf16x8*)(Bgh + go);
            pb1 = *(const bf16x8*)(Bgh + go + 8);
            pb2 = *(const bf16x8*)(Bgl + go);
            pb3 = *(const bf16x8*)(Bgl + go + 8);
        }
        __syncthreads();
        bf16x8 bh[4], bl[4];
        #pragma unroll
        for (int j = 0; j < 4; j++) {
            int c = (wn + j * 16 + fr) * LDR + ko;
            bh[j] = *(const bf16x8*)&Bs[c];
            bl[j] = *(const bf16x8*)&Bs[c + 32];
        }
        #pragma unroll
        for (int i = 0; i < 2; i++) {
            int r = (wm + i * 16 + fr) * LDR + ko;
            bf16x8 ah = *(const bf16x8*)&As[r];
            bf16x8 al = *(const bf16x8*)&As[r + 32];
            #pragma unroll
            for (int j = 0; j < 4; j++) {
                acc[i][j] = __builtin_amdgcn_mfma_f32_16x16x32_bf16(ah, bh[j], acc[i][j], 0, 0, 0);
                acc[i][j] = __builtin_amdgcn_mfma_f32_16x16x32_bf16(ah, bl[j], acc[i][j], 0, 0, 0);
                acc[i][j] = __builtin_amdgcn_mfma_f32_16x16x32_bf16(al, bh[j], acc[i][j], 0, 0, 0);
            }
        }
        __syncthreads();
    }
    long MN = (long)M * Nn;
    float* Pp = part + (long)s * MN;
    int cr = (lane >> 4) * 4;
    #pragma unroll
    for (int i = 0; i < 2; i++) {
        #pragma unroll
        for (int r = 0; r < 4; r++) {
            int gm = m0 + wm + i * 16 + cr + r;
            if (gm >= M) continue;
            float* rowp = &Pp[(long)gm * Nn + n0 + wn + fr];
            #pragma unroll
            for (int j = 0; j < 4; j++) rowp[j * 16] = acc[i][j][r];
        }
    }
}

// ======== fused flash attention (merged PV passes): per (q-block 64, head), 2 waves ========
__global__ __launch_bounds__(128) void flash_attn_kernel(
    const short* __restrict__ qh, const short* __restrict__ ql,
    const short* __restrict__ kh, const short* __restrict__ kl,
    const short* __restrict__ vth, const short* __restrict__ vtl,
    const float* __restrict__ mb,
    short* __restrict__ ctxh, short* __restrict__ ctxl)
{
    __shared__ short Qs[2 * 64 * LDR];   // 18432 B
    __shared__ short Ks[128 * LDR];      // 18432 B (K tile or V tile)
    __shared__ short Psh[4 * 64 * 40];   // 20480 B  P hi
    __shared__ short Psl[4 * 64 * 40];   // 20480 B  P lo
    int h = blockIdx.y;
    int q0 = blockIdx.x * 64;
    int tid = threadIdx.x;               // 128
    int wid = tid >> 6, lane = tid & 63;
    int wm = wid * 32;
    int fr = lane & 15, ko = (lane >> 4) * 8;
    int cr4 = (lane >> 4) * 4;
    // ---- stage Q once
    {
        int row = tid >> 1, dseg = tid & 1;
        const short* gh_ = qh + (long)(q0 + row) * kH + h * kDH + dseg * 32;
        const short* gl_ = ql + (long)(q0 + row) * kH + h * kDH + dseg * 32;
        short* dst = &Qs[(dseg * 64 + row) * LDR];
        #pragma unroll
        for (int c = 0; c < 4; c++) {
            *(bf16x8*)&dst[c * 8]      = *(const bf16x8*)(gh_ + c * 8);
            *(bf16x8*)&dst[32 + c * 8] = *(const bf16x8*)(gl_ + c * 8);
        }
    }
    float mrun[2][4], lrun[2][4];
    f32x4 accO[2][4];
    #pragma unroll
    for (int i = 0; i < 2; i++)
        #pragma unroll
        for (int r = 0; r < 4; r++) { mrun[i][r] = -1e30f; lrun[i][r] = 0.f; }
    #pragma unroll
    for (int i = 0; i < 2; i++)
        #pragma unroll
        for (int j = 0; j < 4; j++) accO[i][j] = (f32x4){0.f, 0.f, 0.f, 0.f};

    for (int t = 0; t < 4; ++t) {
        int k0t = t * 128;
        // ---- S = Q K^T over d (2 k-steps of 32) ----
        f32x4 accS[2][8];
        #pragma unroll
        for (int i = 0; i < 2; i++)
            #pragma unroll
            for (int j = 0; j < 8; j++) accS[i][j] = (f32x4){0.f, 0.f, 0.f, 0.f};
        for (int st = 0; st < 2; ++st) {
            __syncthreads();
            {   // stage K tile
                int row = tid;
                const short* gh_ = kh + (long)(k0t + row) * kH + h * kDH + st * 32;
                const short* gl_ = kl + (long)(k0t + row) * kH + h * kDH + st * 32;
                short* dst = &Ks[row * LDR];
                #pragma unroll
                for (int c = 0; c < 4; c++) {
                    *(bf16x8*)&dst[c * 8]      = *(const bf16x8*)(gh_ + c * 8);
                    *(bf16x8*)&dst[32 + c * 8] = *(const bf16x8*)(gl_ + c * 8);
                }
            }
            __syncthreads();
            bf16x8 bh[8], bl[8];
            #pragma unroll
            for (int j = 0; j < 8; j++) {
                int c = (j * 16 + fr) * LDR + ko;
                bh[j] = *(const bf16x8*)&Ks[c];
                bl[j] = *(const bf16x8*)&Ks[c + 32];
            }
            #pragma unroll
            for (int i = 0; i < 2; i++) {
                int r = (st * 64 + wm + i * 16 + fr) * LDR + ko;
                bf16x8 ah = *(const bf16x8*)&Qs[r];
                bf16x8 al = *(const bf16x8*)&Qs[r + 32];
                #pragma unroll
                for (int j = 0; j < 8; j++) {
                    accS[i][j] = __builtin_amdgcn_mfma_f32_16x16x32_bf16(ah, bh[j], accS[i][j], 0, 0, 0);
                    accS[i][j] = __builtin_amdgcn_mfma_f32_16x16x32_bf16(ah, bl[j], accS[i][j], 0, 0, 0);
                    accS[i][j] = __builtin_amdgcn_mfma_f32_16x16x32_bf16(al, bh[j], accS[i][j], 0, 0, 0);
                }
            }
        }
        // ---- online softmax ----
        float mbv[8];
        #pragma unroll
        for (int j = 0; j < 8; j++) mbv[j] = mb[k0t + j * 16 + fr];
        #pragma unroll
        for (int i = 0; i < 2; i++) {
            #pragma unroll
            for (int r = 0; r < 4; r++) {
                float mt = -1e30f;
                #pragma unroll
                for (int j = 0; j < 8; j++) {
                    float sv = accS[i][j][r] * 0.125f + mbv[j];
                    accS[i][j][r] = sv;
                    mt = fmaxf(mt, sv);
                }
                #pragma unroll
                for (int mmask = 1; mmask < 16; mmask <<= 1)
                    mt = fmaxf(mt, __shfl_xor(mt, mmask, 64));
                float mn = fmaxf(mrun[i][r], mt);
                float sc = __expf(mrun[i][r] - mn);
                mrun[i][r] = mn;
                lrun[i][r] *= sc;
                #pragma unroll
                for (int jo = 0; jo < 4; jo++) accO[i][jo][r] *= sc;
                float lt = 0.f;
                #pragma unroll
                for (int j = 0; j < 8; j++) {
                    float p = __expf(accS[i][j][r] - mn);
                    accS[i][j][r] = p;
                    lt += p;
                }
                #pragma unroll
                for (int mmask = 1; mmask < 16; mmask <<= 1)
                    lt += __shfl_xor(lt, mmask, 64);
                lrun[i][r] += lt;
            }
        }
        // ---- write P hi AND lo to LDS (one pass) ----
        #pragma unroll
        for (int i = 0; i < 2; i++)
            #pragma unroll
            for (int j = 0; j < 8; j++)
                #pragma unroll
                for (int r = 0; r < 4; r++) {
                    int rowp = wm + i * 16 + cr4 + r;
                    int idx = (j >> 1) * 2560 + rowp * 40 + (j & 1) * 16 + fr;
                    float p = accS[i][j][r];
                    unsigned short ph = bf16_rne(p);
                    Psh[idx] = (short)ph;
                    Psl[idx] = (short)bf16_rne(p - bf16_f32(ph));
                }
        // ---- merged PV: per 32-kv step, 3 MFMA terms ----
        for (int st2 = 0; st2 < 4; ++st2) {
            __syncthreads();
            {   // stage V hi+lo: 64 d rows x 32 kv
                int row = tid >> 1, half = tid & 1;
                const short* gh_ = vth + ((long)h * kDH + row) * kS + k0t + st2 * 32 + half * 16;
                const short* gl_ = vtl + ((long)h * kDH + row) * kS + k0t + st2 * 32 + half * 16;
                short* dst = &Ks[row * LDR + half * 16];
                *(bf16x8*)&dst[0]  = *(const bf16x8*)(gh_);
                *(bf16x8*)&dst[8]  = *(const bf16x8*)(gh_ + 8);
                *(bf16x8*)&dst[32] = *(const bf16x8*)(gl_);
                *(bf16x8*)&dst[40] = *(const bf16x8*)(gl_ + 8);
            }
            __syncthreads();
            bf16x8 vh_[4], vl_[4];
            #pragma unroll
            for (int j = 0; j < 4; j++) {
                int c = (j * 16 + fr) * LDR + ko;
                vh_[j] = *(const bf16x8*)&Ks[c];
                vl_[j] = *(const bf16x8*)&Ks[c + 32];
            }
            #pragma unroll
            for (int i = 0; i < 2; i++) {
                int pidx = st2 * 2560 + (wm + i * 16 + fr) * 40 + ko;
                bf16x8 pah = *(const bf16x8*)&Psh[pidx];
                bf16x8 pal = *(const bf16x8*)&Psl[pidx];
                #pragma unroll
                for (int j = 0; j < 4; j++) {
                    accO[i][j] = __builtin_amdgcn_mfma_f32_16x16x32_bf16(pah, vh_[j], accO[i][j], 0, 0, 0);
                    accO[i][j] = __builtin_amdgcn_mfma_f32_16x16x32_bf16(pah, vl_[j], accO[i][j], 0, 0, 0);
                    accO[i][j] = __builtin_amdgcn_mfma_f32_16x16x32_bf16(pal, vh_[j], accO[i][j], 0, 0, 0);
                }
            }
        }
        __syncthreads();   // protect Ps/Ks before next tile
    }
    // ---- finalize ----
    #pragma unroll
    for (int i = 0; i < 2; i++) {
        #pragma unroll
        for (int r = 0; r < 4; r++) {
            float inv = 1.f / lrun[i][r];
            int q = q0 + wm + i * 16 + cr4 + r;
            #pragma unroll
            for (int j = 0; j < 4; j++) {
                float o = accO[i][j][r] * inv;
                int col = h * kDH + j * 16 + fr;
                short hi, lo; split2(o, hi, lo);
                ctxh[(long)q * kH + col] = hi;
                ctxl[(long)q * kH + col] = lo;
            }
        }
    }
}

// ---------------- QKV epilogue: sum partials + bias -> hi/lo shorts ----------------
__global__ void splitk_epi_qkv_kernel(const float* __restrict__ part, Ptr3 bias,
                                      short* __restrict__ qh, short* __restrict__ ql,
                                      short* __restrict__ kh, short* __restrict__ kl,
                                      short* __restrict__ vh, short* __restrict__ vl,
                                      int S) {
    const long MN = (long)kS * kH;
    int w = blockIdx.y;
    long i = ((long)blockIdx.x * blockDim.x + threadIdx.x) * 4;
    if (i >= MN) return;
    const float* P = part + (long)w * S * MN + i;
    float4 a = *(const float4*)P;
    for (int s2 = 1; s2 < S; ++s2) {
        float4 b2 = *(const float4*)(P + (long)s2 * MN);
        a.x += b2.x; a.y += b2.y; a.z += b2.z; a.w += b2.w;
    }
    const float* bw = bias.p[w];
    int n = (int)(i % kH);
    a.x += bw[n]; a.y += bw[n + 1]; a.z += bw[n + 2]; a.w += bw[n + 3];
    short* oh = (w == 0) ? qh : (w == 1) ? kh : vh;
    short* ol = (w == 0) ? ql : (w == 1) ? kl : vl;
    short h0, l0, h1, l1, h2, l2, h3, l3;
    split2(a.x, h0, l0); split2(a.y, h1, l1); split2(a.z, h2, l2); split2(a.w, h3, l3);
    *(short4*)&oh[i] = make_short4(h0, h1, h2, h3);
    *(short4*)&ol[i] = make_short4(l0, l1, l2, l3);
}

// ---------------- generic epilogue: sum partials (+bias, +act) -> hi/lo shorts ----------------
__global__ void splitk_epi_sh_kernel(const float* __restrict__ part, const float* __restrict__ bias,
                                     short* __restrict__ oh, short* __restrict__ ol,
                                     long MN, int Nn, int S, int act) {
    long i = ((long)blockIdx.x * blockDim.x + threadIdx.x) * 4;
    if (i >= MN) return;
    const float* P = part + i;
    float4 a = *(const float4*)P;
    for (int s2 = 1; s2 < S; ++s2) {
        float4 b2 = *(const float4*)(P + (long)s2 * MN);
        a.x += b2.x; a.y += b2.y; a.z += b2.z; a.w += b2.w;
    }
    if (bias) {
        int n = (int)(i % Nn);
        a.x += bias[n]; a.y += bias[n + 1]; a.z += bias[n + 2]; a.w += bias[n + 3];
    }
    if (act == 1) {
        a.x = 0.5f * a.x * (1.f + erff(a.x * 0.70710678118654752f));
        a.y = 0.5f * a.y * (1.f + erff(a.y * 0.70710678118654752f));
        a.z = 0.5f * a.z * (1.f + erff(a.z * 0.70710678118654752f));
        a.w = 0.5f * a.w * (1.f + erff(a.w * 0.70710678118654752f));
    }
    short h0, l0, h1, l1, h2, l2, h3, l3;
    split2(a.x, h0, l0); split2(a.y, h1, l1); split2(a.z, h2, l2); split2(a.w, h3, l3);
    *(short4*)&oh[i] = make_short4(h0, h1, h2, h3);
    *(short4*)&ol[i] = make_short4(l0, l1, l2, l3);
}

// ---------------- fused split-K + bias + residual + LN -> fp32 + hi/lo ----------------
__global__ void splitk_epi_ln2_kernel(const float* __restrict__ part, const float* __restrict__ bias,
                                      const float* __restrict__ res, const float* __restrict__ g,
                                      const float* __restrict__ b, float* __restrict__ out,
                                      short* __restrict__ oh, short* __restrict__ ol, int S) {
    int row = blockIdx.x; int tid = threadIdx.x;
    __shared__ float red[256];
    const long MN = (long)kS * kH;
    float vals[3]; float sum = 0.f;
    #pragma unroll
    for (int r = 0; r < 3; r++) {
        int j = tid + r * 256;
        const float* P = part + (long)row * kH + j;
        float x = res[(long)row * kH + j] + bias[j];
        for (int s2 = 0; s2 < S; ++s2) x += P[(long)s2 * MN];
        vals[r] = x; sum += x;
    }
    red[tid] = sum; __syncthreads();
    for (int off = 128; off > 0; off >>= 1) { if (tid < off) red[tid] += red[tid + off]; __syncthreads(); }
    float mean = red[0] / kH; __syncthreads();
    float vs = 0.f;
    #pragma unroll
    for (int r = 0; r < 3; r++) { float d = vals[r] - mean; vs += d * d; }
    red[tid] = vs; __syncthreads();
    for (int off = 128; off > 0; off >>= 1) { if (tid < off) red[tid] += red[tid + off]; __syncthreads(); }
    float rstd = rsqrtf(red[0] / kH + 1e-12f);
    #pragma unroll
    for (int r = 0; r < 3; r++) {
        int j = tid + r * 256;
        float o = (vals[r] - mean) * rstd * g[j] + b[j];
        out[(long)row * kH + j] = o;
        short hi, lo; split2(o, hi, lo);
        oh[(long)row * kH + j] = hi; ol[(long)row * kH + j] = lo;
    }
}

// ---------------- GCN sparse kernels ----------------
__global__ void cnt_kernel(const int* __restrict__ dst, int* __restrict__ cnt, int E) {
    int e = blockIdx.x * blockDim.x + threadIdx.x;
    if (e < E) atomicAdd(&cnt[dst[e]], 1);
}

__global__ void scan1_kernel(const int* __restrict__ cnt, int* __restrict__ offs,
                             int* __restrict__ bsum, int n) {
    __shared__ int sh[256];
    int i = blockIdx.x * 256 + threadIdx.x;
    int v = (i < n) ? cnt[i] : 0;
    sh[threadIdx.x] = v; __syncthreads();
    for (int off = 1; off < 256; off <<= 1) {
        int t = (threadIdx.x >= off) ? sh[threadIdx.x - off] : 0;
        __syncthreads();
        sh[threadIdx.x] += t;
        __syncthreads();
    }
    if (i < n) offs[i] = sh[threadIdx.x] - v;
    if (threadIdx.x == 255) bsum[blockIdx.x] = sh[255];
}

__global__ void scan2_kernel(int* bsum, int nb, int* offs, int n) {
    if (threadIdx.x == 0) {
        int run = 0;
        for (int b = 0; b < nb; b++) { int t = bsum[b]; bsum[b] = run; run += t; }
        offs[n] = run;
    }
}

__global__ void scan3_kernel(const int* __restrict__ cnt, int* __restrict__ offs,
                             const int* __restrict__ bsum, int* __restrict__ cur,
                             float* __restrict__ dinv, int n) {
    int i = blockIdx.x * 256 + threadIdx.x;
    if (i >= n) return;
    int o = offs[i] + bsum[blockIdx.x];
    offs[i] = o; cur[i] = o;
    dinv[i] = rsqrtf((float)(cnt[i] + 1));
}

__global__ void csrfill_edgew_kernel(const int* __restrict__ src, const int* __restrict__ dst,
                                     int* __restrict__ cur, int* __restrict__ csr,
                                     const float* __restrict__ dinv, float* __restrict__ wsum,
                                     int E) {
    int e = blockIdx.x * blockDim.x + threadIdx.x;
    if (e < E) {
        int s2 = src[e], d = dst[e];
        int slot = atomicAdd(&cur[d], 1);
        csr[slot] = s2;
        atomicAdd(&wsum[s2], dinv[s2] * dinv[d]);
    }
}

// gather SpMM + fused self-loop/bias/relu, 8-way ILP unroll
__global__ __launch_bounds__(256) void spmm_gather_kernel(const int* __restrict__ offs,
                                                          const int* __restrict__ csr,
                                                          const float* __restrict__ dinv,
                                                          const float* __restrict__ hw,
                                                          const float* __restrict__ b1,
                                                          float* __restrict__ hout, int n) {
    int d = blockIdx.x * 2 + (threadIdx.x >> 7);
    int j = threadIdx.x & 127;
    if (d >= n) return;
    int beg = offs[d], end = offs[d + 1];
    float a0 = 0.f, a1 = 0.f, a2 = 0.f, a3 = 0.f;
    float a4 = 0.f, a5 = 0.f, a6 = 0.f, a7 = 0.f;
    int p = beg;
    for (; p + 8 <= end; p += 8) {
        int s0 = csr[p], s1 = csr[p + 1], s2 = csr[p + 2], s3 = csr[p + 3];
        int s4 = csr[p + 4], s5 = csr[p + 5], s6 = csr[p + 6], s7 = csr[p + 7];
        a0 += dinv[s0] * hw[(long)s0 * kGH + j];
        a1 += dinv[s1] * hw[(long)s1 * kGH + j];
        a2 += dinv[s2] * hw[(long)s2 * kGH + j];
        a3 += dinv[s3] * hw[(long)s3 * kGH + j];
        a4 += dinv[s4] * hw[(long)s4 * kGH + j];
        a5 += dinv[s5] * hw[(long)s5 * kGH + j];
        a6 += dinv[s6] * hw[(long)s6 * kGH + j];
        a7 += dinv[s7] * hw[(long)s7 * kGH + j];
    }
    for (; p < end; ++p) {
        int s8 = csr[p];
        a0 += dinv[s8] * hw[(long)s8 * kGH + j];
    }
    float acc = ((a0 + a1) + (a2 + a3)) + ((a4 + a5) + (a6 + a7));
    float dd = dinv[d];
    float v = acc * dd + dd * dd * hw[(long)d * kGH + j] + b1[j];
    hout[(long)d * kGH + j] = fmaxf(v, 0.f);
}

__global__ void wreduce_kernel(const float* __restrict__ h, const float* __restrict__ w,
                               const float* __restrict__ dinv, float* __restrict__ s, int n) {
    int tid = threadIdx.x; int j = tid & 127; int half = tid >> 7;
    float acc = 0.f;
    for (int u = blockIdx.x * 2 + half; u < n; u += gridDim.x * 2) {
        float di = dinv[u];
        acc += (w[u] + di * di) * h[(long)u * kGH + j];
    }
    __shared__ float red[256];
    red[tid] = acc; __syncthreads();
    if (tid < 128) atomicAdd(&s[j], red[tid] + red[tid + 128]);
}

__global__ void gcn_final_kernel(const float* s, const float* W2, const float* b2, float* g) {
    int j2 = threadIdx.x;
    float acc = 0.f;
    for (int j = 0; j < kGH; j++) acc += s[j] * W2[(long)j * kGH + j2];
    g[j2] = acc * (1.f / (float)kN) + b2[j2];
}

// ---------------- combine head ----------------
__global__ void combine_part_kernel(const float* __restrict__ cls, const float* __restrict__ gp,
                                    const float* __restrict__ gh, const float* __restrict__ Wc,
                                    float* __restrict__ feat) {
    int i0 = blockIdx.x * 32;
    int tid = threadIdx.x;
    float a0 = 0.f, a1 = 0.f, a2 = 0.f;
    for (int r = 0; r < 32; r++) {
        int i = i0 + r;
        float x = (i < 768) ? cls[i] : (i < 896) ? gp[i - 768]
                : (i < 1664) ? cls[i - 896] : gh[i - 1664];
        const float* row = Wc + (long)i * kH;
        a0 += x * row[tid]; a1 += x * row[tid + 256]; a2 += x * row[tid + 512];
    }
    atomicAdd(&feat[tid], a0);
    atomicAdd(&feat[tid + 256], a1);
    atomicAdd(&feat[tid + 512], a2);
}

// fused: bias+relu on feat, then classifier dot
__global__ void cls_head_kernel(const float* feat, const float* bc,
                                const float* W, const float* b, float* out) {
    int tid = threadIdx.x;
    float a0 = 0.f, a1 = 0.f, a2 = 0.f;
    for (int o = tid; o < kH; o += 256) {
        float f = fmaxf(feat[o] + bc[o], 0.f);
        a0 += f * W[o * 3 + 0]; a1 += f * W[o * 3 + 1]; a2 += f * W[o * 3 + 2];
    }
    __shared__ float r0[256], r1[256], r2[256];
    r0[tid] = a0; r1[tid] = a1; r2[tid] = a2; __syncthreads();
    for (int off = 128; off > 0; off >>= 1) {
        if (tid < off) { r0[tid] += r0[tid + off]; r1[tid] += r1[tid + off]; r2[tid] += r2[tid + off]; }
        __syncthreads();
    }
    if (tid == 0) { out[0] = r0[0] + b[0]; out[1] = r1[0] + b[1]; out[2] = r2[0] + b[2]; }
}

// ---------------- launch ----------------
extern "C" void kernel_launch(void* const* d_in, const int* in_sizes, int n_in,
                              void* d_out, int out_size, void* d_ws, size_t ws_size,
                              hipStream_t stream) {
    const int*   input_ids = (const int*)d_in[0];
    const int*   attn_mask = (const int*)d_in[1];
    const int*   type_ids  = (const int*)d_in[2];
    const int*   p_edges   = (const int*)d_in[3];
    const int*   h_edges   = (const int*)d_in[4];
    const float* p_nodes   = (const float*)d_in[5];
    const float* h_nodes   = (const float*)d_in[6];
    const float* word_emb  = (const float*)d_in[7];
    const float* pos_emb   = (const float*)d_in[8];
    const float* type_emb  = (const float*)d_in[9];
    const float* eln_s     = (const float*)d_in[10];
    const float* eln_b     = (const float*)d_in[11];
    const float* Wq = (const float*)d_in[12]; const float* bq = (const float*)d_in[13];
    const float* Wk = (const float*)d_in[14]; const float* bk = (const float*)d_in[15];
    const float* Wv = (const float*)d_in[16]; const float* bv = (const float*)d_in[17];
    const float* Wo = (const float*)d_in[18]; const float* bo = (const float*)d_in[19];
    const float* l1s = (const float*)d_in[20]; const float* l1b = (const float*)d_in[21];
    const float* W1 = (const float*)d_in[22]; const float* b1 = (const float*)d_in[23];
    const float* W2 = (const float*)d_in[24]; const float* b2 = (const float*)d_in[25];
    const float* l2s = (const float*)d_in[26]; const float* l2b = (const float*)d_in[27];
    const float* gW1 = (const float*)d_in[28]; const float* gb1 = (const float*)d_in[29];
    const float* gW2 = (const float*)d_in[30]; const float* gb2 = (const float*)d_in[31];
    const float* cW  = (const float*)d_in[32]; const float* cb  = (const float*)d_in[33];
    const float* clsW = (const float*)d_in[34]; const float* clsB = (const float*)d_in[35];
    float* out = (float*)d_out;

    // ---------------- workspace layout ----------------
    float* W = (float*)d_ws;
    size_t off = 0;
    auto alloc = [&](size_t n) { float* p = W + off; off += n; return p; };
    float* h    = alloc((size_t)kS * kH);
    float* h1   = alloc((size_t)kS * kH);
    float* deg  = alloc(kN);
    float* wsum = alloc(kN);
    float* svec = alloc(kGH);
    float* gp   = alloc(kGH);
    float* ghv  = alloc(kGH);
    float* mb   = alloc(kS);
    float* feat = alloc(kH);
    float* big  = W + off;

    // BERT-phase big layout (float slots)
    float* part  = big;
    short* ffn1_h = (short*)(big + 7864320);
    short* ffn1_l = ffn1_h + (size_t)1572864;
    short* sm    = (short*)(big + 11796480);
    const size_t SMN = (size_t)kS * kH;
    short* q_h = sm;            short* q_l = q_h + SMN;
    short* k_h = q_l + SMN;     short* k_l = k_h + SMN;
    short* v_h = k_l + SMN;     short* v_l = v_h + SMN;
    short* vt_h = v_l + SMN;    short* vt_l = vt_h + SMN;
    short* ctx_h = vt_l + SMN;  short* ctx_l = ctx_h + SMN;
    short* h1_h = ctx_l + SMN;  short* h1_l = h1_h + SMN;
    short* hh_h = h1_l + SMN;   short* hh_l = hh_h + SMN;

    // GCN-phase overlay on big
    float* hw1 = big;
    float* agg = big + (size_t)kN * kGH;
    int* icnt  = (int*)(big + 2 * (size_t)kN * kGH);
    int* ioffs = icnt + 50048;
    int* icur  = ioffs + 50048;
    int* ibsum = icur + 50048;
    int* icsr  = ibsum + 256;
    short* gwt_h = (short*)(icsr + kE);
    short* gwt_l = gwt_h + (size_t)kH * kGH;

    // Persistent pre-converted weight cache (beyond both overlays)
    const size_t QKV_SZ = (size_t)kH * kH;      // 589824
    const size_t FF_SZ  = (size_t)kH * kF;      // 2359296
    short* wc = (short*)(big + 15000000);
    short* qkv_h = wc;                          short* qkv_l = qkv_h + 12 * 3 * QKV_SZ;
    short* wo_h  = qkv_l + 12 * 3 * QKV_SZ;     short* wo_l  = wo_h + 12 * QKV_SZ;
    short* w1_h  = wo_l + 12 * QKV_SZ;          short* w1_l  = w1_h + 12 * FF_SZ;
    short* w2_h  = w1_l + 12 * FF_SZ;           short* w2_l  = w2_h + 12 * FF_SZ;

    const long MN_H = (long)kS * kH;   // 393216
    const long MN_F = (long)kS * kF;   // 1572864
    const int nScanBlk = CDIV(kN, 256);

    // ---------- pre-convert ALL weights once ----------
    wtrans_all_kernel<<<dim3(24, 24, 12), 256, 0, stream>>>(Wq, qkv_h,              qkv_l,              kH, kH, (long)(3 * QKV_SZ));
    wtrans_all_kernel<<<dim3(24, 24, 12), 256, 0, stream>>>(Wk, qkv_h + QKV_SZ,     qkv_l + QKV_SZ,     kH, kH, (long)(3 * QKV_SZ));
    wtrans_all_kernel<<<dim3(24, 24, 12), 256, 0, stream>>>(Wv, qkv_h + 2 * QKV_SZ, qkv_l + 2 * QKV_SZ, kH, kH, (long)(3 * QKV_SZ));
    wtrans_all_kernel<<<dim3(24, 24, 12), 256, 0, stream>>>(Wo, wo_h, wo_l, kH, kH, (long)QKV_SZ);
    wtrans_all_kernel<<<dim3(96, 24, 12), 256, 0, stream>>>(W1, w1_h, w1_l, kH, kF, (long)FF_SZ);
    wtrans_all_kernel<<<dim3(24, 96, 12), 256, 0, stream>>>(W2, w2_h, w2_l, kF, kH, (long)FF_SZ);

    // ---------- GCN on both graphs ----------
    const int* gsrc[2] = { p_edges, h_edges };
    const int* gdst[2] = { p_edges + kE, h_edges + kE };
    const float* gx[2] = { p_nodes, h_nodes };
    float* gout[2] = { gp, ghv };
    wtrans_all_kernel<<<dim3(kGH / 32, kH / 32, 1), 256, 0, stream>>>(gW1, gwt_h, gwt_l, kH, kGH, 0);
    for (int gi = 0; gi < 2; gi++) {
        gcn_zero_kernel<<<nScanBlk, 256, 0, stream>>>(icnt, wsum, svec);
        cnt_kernel<<<CDIV(kE, 256), 256, 0, stream>>>(gdst[gi], icnt, kE);
        scan1_kernel<<<nScanBlk, 256, 0, stream>>>(icnt, ioffs, ibsum, kN);
        scan2_kernel<<<1, 64, 0, stream>>>(ibsum, nScanBlk, ioffs, kN);
        scan3_kernel<<<nScanBlk, 256, 0, stream>>>(icnt, ioffs, ibsum, icur, deg, kN);
        csrfill_edgew_kernel<<<CDIV(kE, 256), 256, 0, stream>>>(
            gsrc[gi], gdst[gi], icur, icsr, deg, wsum, kE);
        gemm64_gcn<<<dim3(1, CDIV(kN, 64), 1), 256, 0, stream>>>(
            gx[gi], gwt_h, gwt_l, hw1, kN, kGH, kH, 1);
        spmm_gather_kernel<<<CDIV(kN, 2), 256, 0, stream>>>(ioffs, icsr, deg, hw1, gb1, agg, kN);
        wreduce_kernel<<<512, 256, 0, stream>>>(agg, wsum, deg, svec, kN);
        gcn_final_kernel<<<1, kGH, 0, stream>>>(svec, gW2, gb2, gout[gi]);
    }

    // ---------- BERT ----------
    embed_ln_kernel<<<kS, 256, 0, stream>>>(input_ids, type_ids, attn_mask,
                                            word_emb, pos_emb, type_emb,
                                            eln_s, eln_b, h, hh_h, hh_l, mb, feat);
    for (int l = 0; l < kL; l++) {
        const float* bq_l = bq + (size_t)l * kH;
        const float* bk_l = bk + (size_t)l * kH;
        const float* bv_l = bv + (size_t)l * kH;
        const float* bo_l = bo + (size_t)l * kH;
        const float* b1_l = b1 + (size_t)l * kF;
        const float* b2_l = b2 + (size_t)l * kH;
        const float* l1s_l = l1s + (size_t)l * kH; const float* l1b_l = l1b + (size_t)l * kH;
        const float* l2s_l = l2s + (size_t)l * kH; const float* l2b_l = l2b + (size_t)l * kH;
        const short* qkvh_l = qkv_h + (size_t)l * 3 * QKV_SZ;
        const short* qkvl_l = qkv_l + (size_t)l * 3 * QKV_SZ;
        const short* woh_l = wo_h + (size_t)l * QKV_SZ;
        const short* wol_l = wo_l + (size_t)l * QKV_SZ;
        const short* w1h_l = w1_h + (size_t)l * FF_SZ;
        const short* w1l_l = w1_l + (size_t)l * FF_SZ;
        const short* w2h_l = w2_h + (size_t)l * FF_SZ;
        const short* w2l_l = w2_l + (size_t)l * FF_SZ;

        // QKV: S=4, 3 weights -> 576 blocks, 12 partials
        gemm64_pre<<<dim3(kH / 128, kS / 64, 12), 256, 0, stream>>>(
            hh_h, hh_l, qkvh_l, qkvl_l, (long)QKV_SZ, part, kS, kH, kH, 4);
        splitk_epi_qkv_kernel<<<dim3((int)(MN_H / 4 / 256), 3), 256, 0, stream>>>(
            part, Ptr3{{bq_l, bk_l, bv_l}}, q_h, q_l, k_h, k_l, v_h, v_l, 4);
        vtrans_kernel<<<dim3(kS / 32, kNH * 2), 256, 0, stream>>>(v_h, v_l, vt_h, vt_l);
        // fused flash attention -> ctx hi/lo (96 blocks x 128 threads)
        flash_attn_kernel<<<dim3(kS / 64, kNH), 128, 0, stream>>>(
            q_h, q_l, k_h, k_l, vt_h, vt_l, mb, ctx_h, ctx_l);
        // Wo: S=8 -> 384 blocks; fused epi+bias+residual+LN
        gemm64_pre<<<dim3(kH / 128, kS / 64, 8), 256, 0, stream>>>(
            ctx_h, ctx_l, woh_l, wol_l, 0, part, kS, kH, kH, 8);
        splitk_epi_ln2_kernel<<<kS, 256, 0, stream>>>(part, bo_l, h, l1s_l, l1b_l, h1, h1_h, h1_l, 8);
        // FFN1: S=4 -> 768 blocks, gelu
        gemm64_pre<<<dim3(kF / 128, kS / 64, 4), 256, 0, stream>>>(
            h1_h, h1_l, w1h_l, w1l_l, 0, part, kS, kF, kH, 4);
        splitk_epi_sh_kernel<<<(int)(MN_F / 4 / 256), 256, 0, stream>>>(
            part, b1_l, ffn1_h, ffn1_l, MN_F, kF, 4, 1);
        // FFN2: S=8 -> 384 blocks; fused epi+bias+residual+LN
        gemm64_pre<<<dim3(kH / 128, kS / 64, 8), 256, 0, stream>>>(
            ffn1_h, ffn1_l, w2h_l, w2l_l, 0, part, kS, kH, kF, 8);
        splitk_epi_ln2_kernel<<<kS, 256, 0, stream>>>(part, b2_l, h1, l2s_l, l2b_l, h, hh_h, hh_l, 8);
    }

    // ---------- combine + classifier ----------
    combine_part_kernel<<<56, 256, 0, stream>>>(h, gp, ghv, cW, feat);
    cls_head_kernel<<<1, 256, 0, stream>>>(feat, cb, clsW, clsB, out);
}

// Round 13
// 2383.651 us; speedup vs baseline: 1.0255x; 1.0102x over previous
//
#include <hip/hip_runtime.h>
#include <math.h>

// Problem constants
constexpr int kS = 512, kH = 768, kNH = 12, kDH = 64, kF = 3072, kL = 12;
constexpr int kN = 50000, kE = 800000, kGH = 128;

#define CDIV(a,b) (((a)+(b)-1)/(b))

struct Ptr3 { const float* p[3]; };

typedef __attribute__((ext_vector_type(8))) short bf16x8;
typedef __attribute__((ext_vector_type(4))) float f32x4;

__device__ __forceinline__ unsigned short bf16_rne(float f) {
    unsigned int u = __float_as_uint(f);
    u += 0x7fffu + ((u >> 16) & 1u);
    return (unsigned short)(u >> 16);
}
__device__ __forceinline__ float bf16_f32(unsigned short h) {
    return __uint_as_float(((unsigned int)h) << 16);
}
__device__ __forceinline__ void split2(float f, short& hi, short& lo) {
    unsigned short h = bf16_rne(f);
    hi = (short)h;
    lo = (short)bf16_rne(f - bf16_f32(h));
}

constexpr int LDR = 72;  // LDS row: 32 hi | 32 lo | 8 pad shorts (144 B)

// ---------------- generic fill ----------------
__global__ void fill_kernel(float* p, float v, long n) {
    long i = blockIdx.x * (long)blockDim.x + threadIdx.x;
    if (i < n) p[i] = v;
}

// ---------------- GCN per-graph zero init ----------------
__global__ void gcn_zero_kernel(int* icnt, float* wsum, float* svec) {
    int i = blockIdx.x * 256 + threadIdx.x;
    if (i < kN) { icnt[i] = 0; wsum[i] = 0.f; }
    if (i < kGH) svec[i] = 0.f;
}

// ---------------- embeddings + LN (+ hi/lo emit, + maskbias fold, + feat zero) ----------------
__global__ void embed_ln_kernel(const int* ids, const int* tt, const int* mask,
                                const float* we, const float* pe, const float* te,
                                const float* g, const float* b, float* out,
                                short* oh, short* ol, float* mb, float* feat) {
    int s = blockIdx.x;
    int tid = threadIdx.x;
    __shared__ float red[256];
    if (tid == 0) mb[s] = (1.f - (float)mask[s]) * -1e4f;
    if (s == 0) { feat[tid] = 0.f; feat[tid + 256] = 0.f; feat[tid + 512] = 0.f; }
    int id = ids[s], t = tt[s];
    float vals[3]; float sum = 0.f;
    #pragma unroll
    for (int r = 0; r < 3; r++) {
        int j = tid + r * 256;
        float x = we[(long)id * kH + j] + pe[(long)s * kH + j] + te[(long)t * kH + j];
        vals[r] = x; sum += x;
    }
    red[tid] = sum; __syncthreads();
    for (int off = 128; off > 0; off >>= 1) { if (tid < off) red[tid] += red[tid + off]; __syncthreads(); }
    float mean = red[0] / kH; __syncthreads();
    float vs = 0.f;
    #pragma unroll
    for (int r = 0; r < 3; r++) { float d = vals[r] - mean; vs += d * d; }
    red[tid] = vs; __syncthreads();
    for (int off = 128; off > 0; off >>= 1) { if (tid < off) red[tid] += red[tid + off]; __syncthreads(); }
    float rstd = rsqrtf(red[0] / kH + 1e-12f);
    #pragma unroll
    for (int r = 0; r < 3; r++) {
        int j = tid + r * 256;
        float o = (vals[r] - mean) * rstd * g[j] + b[j];
        out[(long)s * kH + j] = o;
        short hi, lo; split2(o, hi, lo);
        oh[(long)s * kH + j] = hi; ol[(long)s * kH + j] = lo;
    }
}

// ---------------- batched weight transpose + split ----------------
__global__ void wtrans_all_kernel(const float* __restrict__ W, short* __restrict__ Th,
                                  short* __restrict__ Tl, int K, int N, long ostride) {
    int z = blockIdx.z;
    const float* Wm = W + (long)z * K * N;
    long moff = (long)z * ostride;
    __shared__ short th[32][33], tl[32][33];
    int n0 = blockIdx.x * 32, k0 = blockIdx.y * 32;
    int c = threadIdx.x & 31, r = threadIdx.x >> 5;
    #pragma unroll
    for (int p = 0; p < 4; p++) {
        int rr = p * 8 + r;
        float f = Wm[(long)(k0 + rr) * N + n0 + c];
        short hi, lo; split2(f, hi, lo);
        th[rr][c] = hi; tl[rr][c] = lo;
    }
    __syncthreads();
    #pragma unroll
    for (int p = 0; p < 4; p++) {
        int rr = p * 8 + r;
        Th[moff + (long)(n0 + rr) * K + k0 + c] = th[c][rr];
        Tl[moff + (long)(n0 + rr) * K + k0 + c] = tl[c][rr];
    }
}

// ---------------- V transpose: v[s][kH] (head slices) -> vt[h][d][s] ----------------
__global__ void vtrans_kernel(const short* __restrict__ vh, const short* __restrict__ vl,
                              short* __restrict__ vth, short* __restrict__ vtl) {
    __shared__ short th[32][33], tl[32][33];
    int s0 = blockIdx.x * 32;
    int h = blockIdx.y >> 1, d0 = (blockIdx.y & 1) * 32;
    int c = threadIdx.x & 31, r = threadIdx.x >> 5;
    #pragma unroll
    for (int p = 0; p < 4; p++) {
        int rr = p * 8 + r;
        th[rr][c] = vh[(long)(s0 + rr) * kH + h * kDH + d0 + c];
        tl[rr][c] = vl[(long)(s0 + rr) * kH + h * kDH + d0 + c];
    }
    __syncthreads();
    #pragma unroll
    for (int p = 0; p < 4; p++) {
        int rr = p * 8 + r;
        vth[((long)h * kDH + d0 + rr) * kS + s0 + c] = th[c][rr];
        vtl[((long)h * kDH + d0 + rr) * kS + s0 + c] = tl[c][rr];
    }
}

// ======== 64x128-tile pre-split MFMA GEMM, register-prefetch double-buffered ========
__global__ __launch_bounds__(256, 4) void gemm64_pre(
    const short* __restrict__ Ah, const short* __restrict__ Al,
    const short* __restrict__ Bth, const short* __restrict__ Btl, long wstride,
    float* __restrict__ part, int M, int Nn, int K, int S)
{
    __shared__ short As[64 * LDR], Bs[128 * LDR];  // 27648 B
    int w = blockIdx.z / S, s = blockIdx.z % S;
    const short* Bh_ = Bth + (long)w * wstride;
    const short* Bl_ = Btl + (long)w * wstride;
    int Kc = K / S, kbeg = s * Kc;
    int m0 = blockIdx.y * 64, n0 = blockIdx.x * 128;
    int tid = threadIdx.x;
    int ar = tid >> 2, aq = (tid & 3) * 8;
    const short* Agh = Ah + (long)(m0 + ar) * K + kbeg + aq;
    const short* Agl = Al + (long)(m0 + ar) * K + kbeg + aq;
    int aofs = ar * LDR + aq;
    int br = tid >> 1, bq = (tid & 1) * 16;
    const short* Bgh = Bh_ + (long)(n0 + br) * K + kbeg + bq;
    const short* Bgl = Bl_ + (long)(n0 + br) * K + kbeg + bq;
    int bofs = br * LDR + bq;
    int wid = tid >> 6, lane = tid & 63;
    int wm = (wid >> 1) * 32, wn = (wid & 1) * 64;
    int fr = lane & 15, ko = (lane >> 4) * 8;
    f32x4 acc[2][4];
    #pragma unroll
    for (int i = 0; i < 2; i++)
        #pragma unroll
        for (int j = 0; j < 4; j++) acc[i][j] = (f32x4){0.f, 0.f, 0.f, 0.f};
    int nst = Kc / 32;
    bf16x8 pa0 = *(const bf16x8*)(Agh);
    bf16x8 pa1 = *(const bf16x8*)(Agl);
    bf16x8 pb0 = *(const bf16x8*)(Bgh);
    bf16x8 pb1 = *(const bf16x8*)(Bgh + 8);
    bf16x8 pb2 = *(const bf16x8*)(Bgl);
    bf16x8 pb3 = *(const bf16x8*)(Bgl + 8);
    for (int st = 0; st < nst; ++st) {
        *(bf16x8*)&As[aofs]      = pa0;
        *(bf16x8*)&As[aofs + 32] = pa1;
        *(bf16x8*)&Bs[bofs]      = pb0;
        *(bf16x8*)&Bs[bofs + 8]  = pb1;
        *(bf16x8*)&Bs[bofs + 32] = pb2;
        *(bf16x8*)&Bs[bofs + 40] = pb3;
        if (st + 1 < nst) {
            int go = (st + 1) * 32;
            pa0 = *(const bf16x8*)(Agh + go);
            pa1 = *(const bf16x8*)(Agl + go);
            pb0 = *(const bf16x8*)(Bgh + go);
            pb1 = *(const bf16x8*)(Bgh + go + 8);
            pb2 = *(const bf16x8*)(Bgl + go);
            pb3 = *(const bf16x8*)(Bgl + go + 8);
        }
        __syncthreads();
        bf16x8 bh[4], bl[4];
        #pragma unroll
        for (int j = 0; j < 4; j++) {
            int c = (wn + j * 16 + fr) * LDR + ko;
            bh[j] = *(const bf16x8*)&Bs[c];
            bl[j] = *(const bf16x8*)&Bs[c + 32];
        }
        #pragma unroll
        for (int i = 0; i < 2; i++) {
            int r = (wm + i * 16 + fr) * LDR + ko;
            bf16x8 ah = *(const bf16x8*)&As[r];
            bf16x8 al = *(const bf16x8*)&As[r + 32];
            #pragma unroll
            for (int j = 0; j < 4; j++) {
                acc[i][j] = __builtin_amdgcn_mfma_f32_16x16x32_bf16(ah, bh[j], acc[i][j], 0, 0, 0);
                acc[i][j] = __builtin_amdgcn_mfma_f32_16x16x32_bf16(ah, bl[j], acc[i][j], 0, 0, 0);
                acc[i][j] = __builtin_amdgcn_mfma_f32_16x16x32_bf16(al, bh[j], acc[i][j], 0, 0, 0);
            }
        }
        __syncthreads();
    }
    long MN = (long)M * Nn;
    float* Pp = part + (long)(w * S + s) * MN;
    int cr = (lane >> 4) * 4;
    #pragma unroll
    for (int i = 0; i < 2; i++) {
        #pragma unroll
        for (int r = 0; r < 4; r++) {
            int gm = m0 + wm + i * 16 + cr + r;
            float* rowp = &Pp[(long)gm * Nn + n0 + wn + fr];
            #pragma unroll
            for (int j = 0; j < 4; j++) rowp[j * 16] = acc[i][j][r];
        }
    }
}

// ======== GCN GEMM: A fp32 inline-split (prefetched), B pre-split; S=1 direct ========
__global__ __launch_bounds__(256, 4) void gemm64_gcn(
    const float* __restrict__ A,
    const short* __restrict__ Bth, const short* __restrict__ Btl,
    float* __restrict__ part, int M, int Nn, int K, int S)
{
    __shared__ short As[64 * LDR], Bs[128 * LDR];
    int s = blockIdx.z;
    int Kc = K / S, kbeg = s * Kc;
    int m0 = blockIdx.y * 64, n0 = blockIdx.x * 128;
    int tid = threadIdx.x;
    int ar = tid >> 2, aqf = (tid & 3) * 8;
    int gmA = m0 + ar; if (gmA > M - 1) gmA = M - 1;
    const float* Agf = A + (long)gmA * K + kbeg + aqf;
    int aofs = ar * LDR + aqf;
    int br = tid >> 1, bq = (tid & 1) * 16;
    const short* Bgh = Bth + (long)(n0 + br) * K + kbeg + bq;
    const short* Bgl = Btl + (long)(n0 + br) * K + kbeg + bq;
    int bofs = br * LDR + bq;
    int wid = tid >> 6, lane = tid & 63;
    int wm = (wid >> 1) * 32, wn = (wid & 1) * 64;
    int fr = lane & 15, ko = (lane >> 4) * 8;
    f32x4 acc[2][4];
    #pragma unroll
    for (int i = 0; i < 2; i++)
        #pragma unroll
        for (int j = 0; j < 4; j++) acc[i][j] = (f32x4){0.f, 0.f, 0.f, 0.f};
    int nst = Kc / 32;
    float4 pf0 = *(const float4*)(Agf);
    float4 pf1 = *(const float4*)(Agf + 4);
    bf16x8 pb0 = *(const bf16x8*)(Bgh);
    bf16x8 pb1 = *(const bf16x8*)(Bgh + 8);
    bf16x8 pb2 = *(const bf16x8*)(Bgl);
    bf16x8 pb3 = *(const bf16x8*)(Bgl + 8);
    for (int st = 0; st < nst; ++st) {
        short h0, l0, h1, l1, h2, l2, h3, l3, h4, l4, h5, l5, h6, l6, h7, l7;
        split2(pf0.x, h0, l0); split2(pf0.y, h1, l1); split2(pf0.z, h2, l2); split2(pf0.w, h3, l3);
        split2(pf1.x, h4, l4); split2(pf1.y, h5, l5); split2(pf1.z, h6, l6); split2(pf1.w, h7, l7);
        *(short4*)&As[aofs]      = make_short4(h0, h1, h2, h3);
        *(short4*)&As[aofs + 4]  = make_short4(h4, h5, h6, h7);
        *(short4*)&As[aofs + 32] = make_short4(l0, l1, l2, l3);
        *(short4*)&As[aofs + 36] = make_short4(l4, l5, l6, l7);
        *(bf16x8*)&Bs[bofs]      = pb0;
        *(bf16x8*)&Bs[bofs + 8]  = pb1;
        *(bf16x8*)&Bs[bofs + 32] = pb2;
        *(bf16x8*)&Bs[bofs + 40] = pb3;
        if (st + 1 < nst) {
            int go = (st + 1) * 32;
            pf0 = *(const float4*)(Agf + go);
            pf1 = *(const float4*)(Agf + go + 4);
            pb0 = *(const bf16x8*)(Bgh + go);
            pb1 = *(const bf16x8*)(Bgh + go + 8);
            pb2 = *(const bf16x8*)(Bgl + go);
            pb3 = *(const bf16x8*)(Bgl + go + 8);
        }
        __syncthreads();
        bf16x8 bh[4], bl[4];
        #pragma unroll
        for (int j = 0; j < 4; j++) {
            int c = (wn + j * 16 + fr) * LDR + ko;
            bh[j] = *(const bf16x8*)&Bs[c];
            bl[j] = *(const bf16x8*)&Bs[c + 32];
        }
        #pragma unroll
        for (int i = 0; i < 2; i++) {
            int r = (wm + i * 16 + fr) * LDR + ko;
            bf16x8 ah = *(const bf16x8*)&As[r];
            bf16x8 al = *(const bf16x8*)&As[r + 32];
            #pragma unroll
            for (int j = 0; j < 4; j++) {
                acc[i][j] = __builtin_amdgcn_mfma_f32_16x16x32_bf16(ah, bh[j], acc[i][j], 0, 0, 0);
                acc[i][j] = __builtin_amdgcn_mfma_f32_16x16x32_bf16(ah, bl[j], acc[i][j], 0, 0, 0);
                acc[i][j] = __builtin_amdgcn_mfma_f32_16x16x32_bf16(al, bh[j], acc[i][j], 0, 0, 0);
            }
        }
        __syncthreads();
    }
    long MN = (long)M * Nn;
    float* Pp = part + (long)s * MN;
    int cr = (lane >> 4) * 4;
    #pragma unroll
    for (int i = 0; i < 2; i++) {
        #pragma unroll
        for (int r = 0; r < 4; r++) {
            int gm = m0 + wm + i * 16 + cr + r;
            if (gm >= M) continue;
            float* rowp = &Pp[(long)gm * Nn + n0 + wn + fr];
            #pragma unroll
            for (int j = 0; j < 4; j++) rowp[j * 16] = acc[i][j][r];
        }
    }
}

// ======== fused flash attention (merged PV passes): per (q-block 64, head), 2 waves ========
__global__ __launch_bounds__(128) void flash_attn_kernel(
    const short* __restrict__ qh, const short* __restrict__ ql,
    const short* __restrict__ kh, const short* __restrict__ kl,
    const short* __restrict__ vth, const short* __restrict__ vtl,
    const float* __restrict__ mb,
    short* __restrict__ ctxh, short* __restrict__ ctxl)
{
    __shared__ short Qs[2 * 64 * LDR];   // 18432 B
    __shared__ short Ks[128 * LDR];      // 18432 B (K tile or V tile)
    __shared__ short Psh[4 * 64 * 40];   // 20480 B  P hi
    __shared__ short Psl[4 * 64 * 40];   // 20480 B  P lo
    int h = blockIdx.y;
    int q0 = blockIdx.x * 64;
    int tid = threadIdx.x;               // 128
    int wid = tid >> 6, lane = tid & 63;
    int wm = wid * 32;
    int fr = lane & 15, ko = (lane >> 4) * 8;
    int cr4 = (lane >> 4) * 4;
    // ---- stage Q once
    {
        int row = tid >> 1, dseg = tid & 1;
        const short* gh_ = qh + (long)(q0 + row) * kH + h * kDH + dseg * 32;
        const short* gl_ = ql + (long)(q0 + row) * kH + h * kDH + dseg * 32;
        short* dst = &Qs[(dseg * 64 + row) * LDR];
        #pragma unroll
        for (int c = 0; c < 4; c++) {
            *(bf16x8*)&dst[c * 8]      = *(const bf16x8*)(gh_ + c * 8);
            *(bf16x8*)&dst[32 + c * 8] = *(const bf16x8*)(gl_ + c * 8);
        }
    }
    float mrun[2][4], lrun[2][4];
    f32x4 accO[2][4];
    #pragma unroll
    for (int i = 0; i < 2; i++)
        #pragma unroll
        for (int r = 0; r < 4; r++) { mrun[i][r] = -1e30f; lrun[i][r] = 0.f; }
    #pragma unroll
    for (int i = 0; i < 2; i++)
        #pragma unroll
        for (int j = 0; j < 4; j++) accO[i][j] = (f32x4){0.f, 0.f, 0.f, 0.f};

    for (int t = 0; t < 4; ++t) {
        int k0t = t * 128;
        // ---- S = Q K^T over d (2 k-steps of 32) ----
        f32x4 accS[2][8];
        #pragma unroll
        for (int i = 0; i < 2; i++)
            #pragma unroll
            for (int j = 0; j < 8; j++) accS[i][j] = (f32x4){0.f, 0.f, 0.f, 0.f};
        for (int st = 0; st < 2; ++st) {
            __syncthreads();
            {   // stage K tile
                int row = tid;
                const short* gh_ = kh + (long)(k0t + row) * kH + h * kDH + st * 32;
                const short* gl_ = kl + (long)(k0t + row) * kH + h * kDH + st * 32;
                short* dst = &Ks[row * LDR];
                #pragma unroll
                for (int c = 0; c < 4; c++) {
                    *(bf16x8*)&dst[c * 8]      = *(const bf16x8*)(gh_ + c * 8);
                    *(bf16x8*)&dst[32 + c * 8] = *(const bf16x8*)(gl_ + c * 8);
                }
            }
            __syncthreads();
            bf16x8 bh[8], bl[8];
            #pragma unroll
            for (int j = 0; j < 8; j++) {
                int c = (j * 16 + fr) * LDR + ko;
                bh[j] = *(const bf16x8*)&Ks[c];
                bl[j] = *(const bf16x8*)&Ks[c + 32];
            }
            #pragma unroll
            for (int i = 0; i < 2; i++) {
                int r = (st * 64 + wm + i * 16 + fr) * LDR + ko;
                bf16x8 ah = *(const bf16x8*)&Qs[r];
                bf16x8 al = *(const bf16x8*)&Qs[r + 32];
                #pragma unroll
                for (int j = 0; j < 8; j++) {
                    accS[i][j] = __builtin_amdgcn_mfma_f32_16x16x32_bf16(ah, bh[j], accS[i][j], 0, 0, 0);
                    accS[i][j] = __builtin_amdgcn_mfma_f32_16x16x32_bf16(ah, bl[j], accS[i][j], 0, 0, 0);
                    accS[i][j] = __builtin_amdgcn_mfma_f32_16x16x32_bf16(al, bh[j], accS[i][j], 0, 0, 0);
                }
            }
        }
        // ---- online softmax ----
        float mbv[8];
        #pragma unroll
        for (int j = 0; j < 8; j++) mbv[j] = mb[k0t + j * 16 + fr];
        #pragma unroll
        for (int i = 0; i < 2; i++) {
            #pragma unroll
            for (int r = 0; r < 4; r++) {
                float mt = -1e30f;
                #pragma unroll
                for (int j = 0; j < 8; j++) {
                    float sv = accS[i][j][r] * 0.125f + mbv[j];
                    accS[i][j][r] = sv;
                    mt = fmaxf(mt, sv);
                }
                #pragma unroll
                for (int mmask = 1; mmask < 16; mmask <<= 1)
                    mt = fmaxf(mt, __shfl_xor(mt, mmask, 64));
                float mn = fmaxf(mrun[i][r], mt);
                float sc = __expf(mrun[i][r] - mn);
                mrun[i][r] = mn;
                lrun[i][r] *= sc;
                #pragma unroll
                for (int jo = 0; jo < 4; jo++) accO[i][jo][r] *= sc;
                float lt = 0.f;
                #pragma unroll
                for (int j = 0; j < 8; j++) {
                    float p = __expf(accS[i][j][r] - mn);
                    accS[i][j][r] = p;
                    lt += p;
                }
                #pragma unroll
                for (int mmask = 1; mmask < 16; mmask <<= 1)
                    lt += __shfl_xor(lt, mmask, 64);
                lrun[i][r] += lt;
            }
        }
        // ---- write P hi AND lo to LDS (one pass) ----
        #pragma unroll
        for (int i = 0; i < 2; i++)
            #pragma unroll
            for (int j = 0; j < 8; j++)
                #pragma unroll
                for (int r = 0; r < 4; r++) {
                    int rowp = wm + i * 16 + cr4 + r;
                    int idx = (j >> 1) * 2560 + rowp * 40 + (j & 1) * 16 + fr;
                    float p = accS[i][j][r];
                    unsigned short ph = bf16_rne(p);
                    Psh[idx] = (short)ph;
                    Psl[idx] = (short)bf16_rne(p - bf16_f32(ph));
                }
        // ---- merged PV: per 32-kv step, 3 MFMA terms ----
        for (int st2 = 0; st2 < 4; ++st2) {
            __syncthreads();
            {   // stage V hi+lo: 64 d rows x 32 kv
                int row = tid >> 1, half = tid & 1;
                const short* gh_ = vth + ((long)h * kDH + row) * kS + k0t + st2 * 32 + half * 16;
                const short* gl_ = vtl + ((long)h * kDH + row) * kS + k0t + st2 * 32 + half * 16;
                short* dst = &Ks[row * LDR + half * 16];
                *(bf16x8*)&dst[0]  = *(const bf16x8*)(gh_);
                *(bf16x8*)&dst[8]  = *(const bf16x8*)(gh_ + 8);
                *(bf16x8*)&dst[32] = *(const bf16x8*)(gl_);
                *(bf16x8*)&dst[40] = *(const bf16x8*)(gl_ + 8);
            }
            __syncthreads();
            bf16x8 vh_[4], vl_[4];
            #pragma unroll
            for (int j = 0; j < 4; j++) {
                int c = (j * 16 + fr) * LDR + ko;
                vh_[j] = *(const bf16x8*)&Ks[c];
                vl_[j] = *(const bf16x8*)&Ks[c + 32];
            }
            #pragma unroll
            for (int i = 0; i < 2; i++) {
                int pidx = st2 * 2560 + (wm + i * 16 + fr) * 40 + ko;
                bf16x8 pah = *(const bf16x8*)&Psh[pidx];
                bf16x8 pal = *(const bf16x8*)&Psl[pidx];
                #pragma unroll
                for (int j = 0; j < 4; j++) {
                    accO[i][j] = __builtin_amdgcn_mfma_f32_16x16x32_bf16(pah, vh_[j], accO[i][j], 0, 0, 0);
                    accO[i][j] = __builtin_amdgcn_mfma_f32_16x16x32_bf16(pah, vl_[j], accO[i][j], 0, 0, 0);
                    accO[i][j] = __builtin_amdgcn_mfma_f32_16x16x32_bf16(pal, vh_[j], accO[i][j], 0, 0, 0);
                }
            }
        }
        __syncthreads();   // protect Ps/Ks before next tile
    }
    // ---- finalize ----
    #pragma unroll
    for (int i = 0; i < 2; i++) {
        #pragma unroll
        for (int r = 0; r < 4; r++) {
            float inv = 1.f / lrun[i][r];
            int q = q0 + wm + i * 16 + cr4 + r;
            #pragma unroll
            for (int j = 0; j < 4; j++) {
                float o = accO[i][j][r] * inv;
                int col = h * kDH + j * 16 + fr;
                short hi, lo; split2(o, hi, lo);
                ctxh[(long)q * kH + col] = hi;
                ctxl[(long)q * kH + col] = lo;
            }
        }
    }
}

// ---------------- QKV epilogue: sum partials + bias -> hi/lo shorts ----------------
__global__ void splitk_epi_qkv_kernel(const float* __restrict__ part, Ptr3 bias,
                                      short* __restrict__ qh, short* __restrict__ ql,
                                      short* __restrict__ kh, short* __restrict__ kl,
                                      short* __restrict__ vh, short* __restrict__ vl,
                                      int S) {
    const long MN = (long)kS * kH;
    int w = blockIdx.y;
    long i = ((long)blockIdx.x * blockDim.x + threadIdx.x) * 4;
    if (i >= MN) return;
    const float* P = part + (long)w * S * MN + i;
    float4 a = *(const float4*)P;
    for (int s2 = 1; s2 < S; ++s2) {
        float4 b2 = *(const float4*)(P + (long)s2 * MN);
        a.x += b2.x; a.y += b2.y; a.z += b2.z; a.w += b2.w;
    }
    const float* bw = bias.p[w];
    int n = (int)(i % kH);
    a.x += bw[n]; a.y += bw[n + 1]; a.z += bw[n + 2]; a.w += bw[n + 3];
    short* oh = (w == 0) ? qh : (w == 1) ? kh : vh;
    short* ol = (w == 0) ? ql : (w == 1) ? kl : vl;
    short h0, l0, h1, l1, h2, l2, h3, l3;
    split2(a.x, h0, l0); split2(a.y, h1, l1); split2(a.z, h2, l2); split2(a.w, h3, l3);
    *(short4*)&oh[i] = make_short4(h0, h1, h2, h3);
    *(short4*)&ol[i] = make_short4(l0, l1, l2, l3);
}

// ---------------- generic epilogue: sum partials (+bias, +act) -> hi/lo shorts ----------------
__global__ void splitk_epi_sh_kernel(const float* __restrict__ part, const float* __restrict__ bias,
                                     short* __restrict__ oh, short* __restrict__ ol,
                                     long MN, int Nn, int S, int act) {
    long i = ((long)blockIdx.x * blockDim.x + threadIdx.x) * 4;
    if (i >= MN) return;
    const float* P = part + i;
    float4 a = *(const float4*)P;
    for (int s2 = 1; s2 < S; ++s2) {
        float4 b2 = *(const float4*)(P + (long)s2 * MN);
        a.x += b2.x; a.y += b2.y; a.z += b2.z; a.w += b2.w;
    }
    if (bias) {
        int n = (int)(i % Nn);
        a.x += bias[n]; a.y += bias[n + 1]; a.z += bias[n + 2]; a.w += bias[n + 3];
    }
    if (act == 1) {
        a.x = 0.5f * a.x * (1.f + erff(a.x * 0.70710678118654752f));
        a.y = 0.5f * a.y * (1.f + erff(a.y * 0.70710678118654752f));
        a.z = 0.5f * a.z * (1.f + erff(a.z * 0.70710678118654752f));
        a.w = 0.5f * a.w * (1.f + erff(a.w * 0.70710678118654752f));
    }
    short h0, l0, h1, l1, h2, l2, h3, l3;
    split2(a.x, h0, l0); split2(a.y, h1, l1); split2(a.z, h2, l2); split2(a.w, h3, l3);
    *(short4*)&oh[i] = make_short4(h0, h1, h2, h3);
    *(short4*)&ol[i] = make_short4(l0, l1, l2, l3);
}

// ---------------- fused split-K + bias + residual + LN -> fp32 + hi/lo ----------------
__global__ void splitk_epi_ln2_kernel(const float* __restrict__ part, const float* __restrict__ bias,
                                      const float* __restrict__ res, const float* __restrict__ g,
                                      const float* __restrict__ b, float* __restrict__ out,
                                      short* __restrict__ oh, short* __restrict__ ol, int S) {
    int row = blockIdx.x; int tid = threadIdx.x;
    __shared__ float red[256];
    const long MN = (long)kS * kH;
    float vals[3]; float sum = 0.f;
    #pragma unroll
    for (int r = 0; r < 3; r++) {
        int j = tid + r * 256;
        const float* P = part + (long)row * kH + j;
        float x = res[(long)row * kH + j] + bias[j];
        for (int s2 = 0; s2 < S; ++s2) x += P[(long)s2 * MN];
        vals[r] = x; sum += x;
    }
    red[tid] = sum; __syncthreads();
    for (int off = 128; off > 0; off >>= 1) { if (tid < off) red[tid] += red[tid + off]; __syncthreads(); }
    float mean = red[0] / kH; __syncthreads();
    float vs = 0.f;
    #pragma unroll
    for (int r = 0; r < 3; r++) { float d = vals[r] - mean; vs += d * d; }
    red[tid] = vs; __syncthreads();
    for (int off = 128; off > 0; off >>= 1) { if (tid < off) red[tid] += red[tid + off]; __syncthreads(); }
    float rstd = rsqrtf(red[0] / kH + 1e-12f);
    #pragma unroll
    for (int r = 0; r < 3; r++) {
        int j = tid + r * 256;
        float o = (vals[r] - mean) * rstd * g[j] + b[j];
        out[(long)row * kH + j] = o;
        short hi, lo; split2(o, hi, lo);
        oh[(long)row * kH + j] = hi; ol[(long)row * kH + j] = lo;
    }
}

// ---------------- GCN sparse kernels ----------------
__global__ void cnt_kernel(const int* __restrict__ dst, int* __restrict__ cnt, int E) {
    int e = blockIdx.x * blockDim.x + threadIdx.x;
    if (e < E) atomicAdd(&cnt[dst[e]], 1);
}

__global__ void scan1_kernel(const int* __restrict__ cnt, int* __restrict__ offs,
                             int* __restrict__ bsum, int n) {
    __shared__ int sh[256];
    int i = blockIdx.x * 256 + threadIdx.x;
    int v = (i < n) ? cnt[i] : 0;
    sh[threadIdx.x] = v; __syncthreads();
    for (int off = 1; off < 256; off <<= 1) {
        int t = (threadIdx.x >= off) ? sh[threadIdx.x - off] : 0;
        __syncthreads();
        sh[threadIdx.x] += t;
        __syncthreads();
    }
    if (i < n) offs[i] = sh[threadIdx.x] - v;
    if (threadIdx.x == 255) bsum[blockIdx.x] = sh[255];
}

__global__ void scan2_kernel(int* bsum, int nb, int* offs, int n) {
    if (threadIdx.x == 0) {
        int run = 0;
        for (int b = 0; b < nb; b++) { int t = bsum[b]; bsum[b] = run; run += t; }
        offs[n] = run;
    }
}

__global__ void scan3_kernel(const int* __restrict__ cnt, int* __restrict__ offs,
                             const int* __restrict__ bsum, int* __restrict__ cur,
                             float* __restrict__ dinv, int n) {
    int i = blockIdx.x * 256 + threadIdx.x;
    if (i >= n) return;
    int o = offs[i] + bsum[blockIdx.x];
    offs[i] = o; cur[i] = o;
    dinv[i] = rsqrtf((float)(cnt[i] + 1));
}

__global__ void csrfill_edgew_kernel(const int* __restrict__ src, const int* __restrict__ dst,
                                     int* __restrict__ cur, int* __restrict__ csr,
                                     const float* __restrict__ dinv, float* __restrict__ wsum,
                                     int E) {
    int e = blockIdx.x * blockDim.x + threadIdx.x;
    if (e < E) {
        int s2 = src[e], d = dst[e];
        int slot = atomicAdd(&cur[d], 1);
        csr[slot] = s2;
        atomicAdd(&wsum[s2], dinv[s2] * dinv[d]);
    }
}

// gather SpMM + fused self-loop/bias/relu, 8-way ILP unroll
__global__ __launch_bounds__(256) void spmm_gather_kernel(const int* __restrict__ offs,
                                                          const int* __restrict__ csr,
                                                          const float* __restrict__ dinv,
                                                          const float* __restrict__ hw,
                                                          const float* __restrict__ b1,
                                                          float* __restrict__ hout, int n) {
    int d = blockIdx.x * 2 + (threadIdx.x >> 7);
    int j = threadIdx.x & 127;
    if (d >= n) return;
    int beg = offs[d], end = offs[d + 1];
    float a0 = 0.f, a1 = 0.f, a2 = 0.f, a3 = 0.f;
    float a4 = 0.f, a5 = 0.f, a6 = 0.f, a7 = 0.f;
    int p = beg;
    for (; p + 8 <= end; p += 8) {
        int s0 = csr[p], s1 = csr[p + 1], s2 = csr[p + 2], s3 = csr[p + 3];
        int s4 = csr[p + 4], s5 = csr[p + 5], s6 = csr[p + 6], s7 = csr[p + 7];
        a0 += dinv[s0] * hw[(long)s0 * kGH + j];
        a1 += dinv[s1] * hw[(long)s1 * kGH + j];
        a2 += dinv[s2] * hw[(long)s2 * kGH + j];
        a3 += dinv[s3] * hw[(long)s3 * kGH + j];
        a4 += dinv[s4] * hw[(long)s4 * kGH + j];
        a5 += dinv[s5] * hw[(long)s5 * kGH + j];
        a6 += dinv[s6] * hw[(long)s6 * kGH + j];
        a7 += dinv[s7] * hw[(long)s7 * kGH + j];
    }
    for (; p < end; ++p) {
        int s8 = csr[p];
        a0 += dinv[s8] * hw[(long)s8 * kGH + j];
    }
    float acc = ((a0 + a1) + (a2 + a3)) + ((a4 + a5) + (a6 + a7));
    float dd = dinv[d];
    float v = acc * dd + dd * dd * hw[(long)d * kGH + j] + b1[j];
    hout[(long)d * kGH + j] = fmaxf(v, 0.f);
}

__global__ void wreduce_kernel(const float* __restrict__ h, const float* __restrict__ w,
                               const float* __restrict__ dinv, float* __restrict__ s, int n) {
    int tid = threadIdx.x; int j = tid & 127; int half = tid >> 7;
    float acc = 0.f;
    for (int u = blockIdx.x * 2 + half; u < n; u += gridDim.x * 2) {
        float di = dinv[u];
        acc += (w[u] + di * di) * h[(long)u * kGH + j];
    }
    __shared__ float red[256];
    red[tid] = acc; __syncthreads();
    if (tid < 128) atomicAdd(&s[j], red[tid] + red[tid + 128]);
}

__global__ void gcn_final_kernel(const float* s, const float* W2, const float* b2, float* g) {
    int j2 = threadIdx.x;
    float acc = 0.f;
    for (int j = 0; j < kGH; j++) acc += s[j] * W2[(long)j * kGH + j2];
    g[j2] = acc * (1.f / (float)kN) + b2[j2];
}

// ---------------- combine head ----------------
__global__ void combine_part_kernel(const float* __restrict__ cls, const float* __restrict__ gp,
                                    const float* __restrict__ gh, const float* __restrict__ Wc,
                                    float* __restrict__ feat) {
    int i0 = blockIdx.x * 32;
    int tid = threadIdx.x;
    float a0 = 0.f, a1 = 0.f, a2 = 0.f;
    for (int r = 0; r < 32; r++) {
        int i = i0 + r;
        float x = (i < 768) ? cls[i] : (i < 896) ? gp[i - 768]
                : (i < 1664) ? cls[i - 896] : gh[i - 1664];
        const float* row = Wc + (long)i * kH;
        a0 += x * row[tid]; a1 += x * row[tid + 256]; a2 += x * row[tid + 512];
    }
    atomicAdd(&feat[tid], a0);
    atomicAdd(&feat[tid + 256], a1);
    atomicAdd(&feat[tid + 512], a2);
}

// fused: bias+relu on feat, then classifier dot
__global__ void cls_head_kernel(const float* feat, const float* bc,
                                const float* W, const float* b, float* out) {
    int tid = threadIdx.x;
    float a0 = 0.f, a1 = 0.f, a2 = 0.f;
    for (int o = tid; o < kH; o += 256) {
        float f = fmaxf(feat[o] + bc[o], 0.f);
        a0 += f * W[o * 3 + 0]; a1 += f * W[o * 3 + 1]; a2 += f * W[o * 3 + 2];
    }
    __shared__ float r0[256], r1[256], r2[256];
    r0[tid] = a0; r1[tid] = a1; r2[tid] = a2; __syncthreads();
    for (int off = 128; off > 0; off >>= 1) {
        if (tid < off) { r0[tid] += r0[tid + off]; r1[tid] += r1[tid + off]; r2[tid] += r2[tid + off]; }
        __syncthreads();
    }
    if (tid == 0) { out[0] = r0[0] + b[0]; out[1] = r1[0] + b[1]; out[2] = r2[0] + b[2]; }
}

// ---------------- launch ----------------
extern "C" void kernel_launch(void* const* d_in, const int* in_sizes, int n_in,
                              void* d_out, int out_size, void* d_ws, size_t ws_size,
                              hipStream_t stream) {
    const int*   input_ids = (const int*)d_in[0];
    const int*   attn_mask = (const int*)d_in[1];
    const int*   type_ids  = (const int*)d_in[2];
    const int*   p_edges   = (const int*)d_in[3];
    const int*   h_edges   = (const int*)d_in[4];
    const float* p_nodes   = (const float*)d_in[5];
    const float* h_nodes   = (const float*)d_in[6];
    const float* word_emb  = (const float*)d_in[7];
    const float* pos_emb   = (const float*)d_in[8];
    const float* type_emb  = (const float*)d_in[9];
    const float* eln_s     = (const float*)d_in[10];
    const float* eln_b     = (const float*)d_in[11];
    const float* Wq = (const float*)d_in[12]; const float* bq = (const float*)d_in[13];
    const float* Wk = (const float*)d_in[14]; const float* bk = (const float*)d_in[15];
    const float* Wv = (const float*)d_in[16]; const float* bv = (const float*)d_in[17];
    const float* Wo = (const float*)d_in[18]; const float* bo = (const float*)d_in[19];
    const float* l1s = (const float*)d_in[20]; const float* l1b = (const float*)d_in[21];
    const float* W1 = (const float*)d_in[22]; const float* b1 = (const float*)d_in[23];
    const float* W2 = (const float*)d_in[24]; const float* b2 = (const float*)d_in[25];
    const float* l2s = (const float*)d_in[26]; const float* l2b = (const float*)d_in[27];
    const float* gW1 = (const float*)d_in[28]; const float* gb1 = (const float*)d_in[29];
    const float* gW2 = (const float*)d_in[30]; const float* gb2 = (const float*)d_in[31];
    const float* cW  = (const float*)d_in[32]; const float* cb  = (const float*)d_in[33];
    const float* clsW = (const float*)d_in[34]; const float* clsB = (const float*)d_in[35];
    float* out = (float*)d_out;

    // ---------------- workspace layout ----------------
    float* W = (float*)d_ws;
    size_t off = 0;
    auto alloc = [&](size_t n) { float* p = W + off; off += n; return p; };
    float* h    = alloc((size_t)kS * kH);
    float* h1   = alloc((size_t)kS * kH);
    float* deg  = alloc(kN);
    float* wsum = alloc(kN);
    float* svec = alloc(kGH);
    float* gp   = alloc(kGH);
    float* ghv  = alloc(kGH);
    float* mb   = alloc(kS);
    float* feat = alloc(kH);
    float* big  = W + off;

    // BERT-phase big layout (float slots)
    float* part  = big;
    short* ffn1_h = (short*)(big + 7864320);
    short* ffn1_l = ffn1_h + (size_t)1572864;
    short* sm    = (short*)(big + 11796480);
    const size_t SMN = (size_t)kS * kH;
    short* q_h = sm;            short* q_l = q_h + SMN;
    short* k_h = q_l + SMN;     short* k_l = k_h + SMN;
    short* v_h = k_l + SMN;     short* v_l = v_h + SMN;
    short* vt_h = v_l + SMN;    short* vt_l = vt_h + SMN;
    short* ctx_h = vt_l + SMN;  short* ctx_l = ctx_h + SMN;
    short* h1_h = ctx_l + SMN;  short* h1_l = h1_h + SMN;
    short* hh_h = h1_l + SMN;   short* hh_l = hh_h + SMN;

    // GCN-phase overlay on big
    float* hw1 = big;
    float* agg = big + (size_t)kN * kGH;
    int* icnt  = (int*)(big + 2 * (size_t)kN * kGH);
    int* ioffs = icnt + 50048;
    int* icur  = ioffs + 50048;
    int* ibsum = icur + 50048;
    int* icsr  = ibsum + 256;
    short* gwt_h = (short*)(icsr + kE);
    short* gwt_l = gwt_h + (size_t)kH * kGH;

    // Persistent pre-converted weight cache (beyond both overlays)
    const size_t QKV_SZ = (size_t)kH * kH;      // 589824
    const size_t FF_SZ  = (size_t)kH * kF;      // 2359296
    short* wc = (short*)(big + 15000000);
    short* qkv_h = wc;                          short* qkv_l = qkv_h + 12 * 3 * QKV_SZ;
    short* wo_h  = qkv_l + 12 * 3 * QKV_SZ;     short* wo_l  = wo_h + 12 * QKV_SZ;
    short* w1_h  = wo_l + 12 * QKV_SZ;          short* w1_l  = w1_h + 12 * FF_SZ;
    short* w2_h  = w1_l + 12 * FF_SZ;           short* w2_l  = w2_h + 12 * FF_SZ;

    const long MN_H = (long)kS * kH;   // 393216
    const long MN_F = (long)kS * kF;   // 1572864
    const int nScanBlk = CDIV(kN, 256);

    // ---------- pre-convert ALL weights once ----------
    wtrans_all_kernel<<<dim3(24, 24, 12), 256, 0, stream>>>(Wq, qkv_h,              qkv_l,              kH, kH, (long)(3 * QKV_SZ));
    wtrans_all_kernel<<<dim3(24, 24, 12), 256, 0, stream>>>(Wk, qkv_h + QKV_SZ,     qkv_l + QKV_SZ,     kH, kH, (long)(3 * QKV_SZ));
    wtrans_all_kernel<<<dim3(24, 24, 12), 256, 0, stream>>>(Wv, qkv_h + 2 * QKV_SZ, qkv_l + 2 * QKV_SZ, kH, kH, (long)(3 * QKV_SZ));
    wtrans_all_kernel<<<dim3(24, 24, 12), 256, 0, stream>>>(Wo, wo_h, wo_l, kH, kH, (long)QKV_SZ);
    wtrans_all_kernel<<<dim3(96, 24, 12), 256, 0, stream>>>(W1, w1_h, w1_l, kH, kF, (long)FF_SZ);
    wtrans_all_kernel<<<dim3(24, 96, 12), 256, 0, stream>>>(W2, w2_h, w2_l, kF, kH, (long)FF_SZ);

    // ---------- GCN on both graphs ----------
    const int* gsrc[2] = { p_edges, h_edges };
    const int* gdst[2] = { p_edges + kE, h_edges + kE };
    const float* gx[2] = { p_nodes, h_nodes };
    float* gout[2] = { gp, ghv };
    wtrans_all_kernel<<<dim3(kGH / 32, kH / 32, 1), 256, 0, stream>>>(gW1, gwt_h, gwt_l, kH, kGH, 0);
    for (int gi = 0; gi < 2; gi++) {
        gcn_zero_kernel<<<nScanBlk, 256, 0, stream>>>(icnt, wsum, svec);
        cnt_kernel<<<CDIV(kE, 256), 256, 0, stream>>>(gdst[gi], icnt, kE);
        scan1_kernel<<<nScanBlk, 256, 0, stream>>>(icnt, ioffs, ibsum, kN);
        scan2_kernel<<<1, 64, 0, stream>>>(ibsum, nScanBlk, ioffs, kN);
        scan3_kernel<<<nScanBlk, 256, 0, stream>>>(icnt, ioffs, ibsum, icur, deg, kN);
        csrfill_edgew_kernel<<<CDIV(kE, 256), 256, 0, stream>>>(
            gsrc[gi], gdst[gi], icur, icsr, deg, wsum, kE);
        gemm64_gcn<<<dim3(1, CDIV(kN, 64), 1), 256, 0, stream>>>(
            gx[gi], gwt_h, gwt_l, hw1, kN, kGH, kH, 1);
        spmm_gather_kernel<<<CDIV(kN, 2), 256, 0, stream>>>(ioffs, icsr, deg, hw1, gb1, agg, kN);
        wreduce_kernel<<<512, 256, 0, stream>>>(agg, wsum, deg, svec, kN);
        gcn_final_kernel<<<1, kGH, 0, stream>>>(svec, gW2, gb2, gout[gi]);
    }

    // ---------- BERT ----------
    embed_ln_kernel<<<kS, 256, 0, stream>>>(input_ids, type_ids, attn_mask,
                                            word_emb, pos_emb, type_emb,
                                            eln_s, eln_b, h, hh_h, hh_l, mb, feat);
    for (int l = 0; l < kL; l++) {
        const float* bq_l = bq + (size_t)l * kH;
        const float* bk_l = bk + (size_t)l * kH;
        const float* bv_l = bv + (size_t)l * kH;
        const float* bo_l = bo + (size_t)l * kH;
        const float* b1_l = b1 + (size_t)l * kF;
        const float* b2_l = b2 + (size_t)l * kH;
        const float* l1s_l = l1s + (size_t)l * kH; const float* l1b_l = l1b + (size_t)l * kH;
        const float* l2s_l = l2s + (size_t)l * kH; const float* l2b_l = l2b + (size_t)l * kH;
        const short* qkvh_l = qkv_h + (size_t)l * 3 * QKV_SZ;
        const short* qkvl_l = qkv_l + (size_t)l * 3 * QKV_SZ;
        const short* woh_l = wo_h + (size_t)l * QKV_SZ;
        const short* wol_l = wo_l + (size_t)l * QKV_SZ;
        const short* w1h_l = w1_h + (size_t)l * FF_SZ;
        const short* w1l_l = w1_l + (size_t)l * FF_SZ;
        const short* w2h_l = w2_h + (size_t)l * FF_SZ;
        const short* w2l_l = w2_l + (size_t)l * FF_SZ;

        // QKV: S=3, 3 weights -> 432 blocks, 9 partials
        gemm64_pre<<<dim3(kH / 128, kS / 64, 9), 256, 0, stream>>>(
            hh_h, hh_l, qkvh_l, qkvl_l, (long)QKV_SZ, part, kS, kH, kH, 3);
        splitk_epi_qkv_kernel<<<dim3((int)(MN_H / 4 / 256), 3), 256, 0, stream>>>(
            part, Ptr3{{bq_l, bk_l, bv_l}}, q_h, q_l, k_h, k_l, v_h, v_l, 3);
        vtrans_kernel<<<dim3(kS / 32, kNH * 2), 256, 0, stream>>>(v_h, v_l, vt_h, vt_l);
        // fused flash attention -> ctx hi/lo (96 blocks x 128 threads)
        flash_attn_kernel<<<dim3(kS / 64, kNH), 128, 0, stream>>>(
            q_h, q_l, k_h, k_l, vt_h, vt_l, mb, ctx_h, ctx_l);
        // Wo: S=8 -> 384 blocks; fused epi+bias+residual+LN
        gemm64_pre<<<dim3(kH / 128, kS / 64, 8), 256, 0, stream>>>(
            ctx_h, ctx_l, woh_l, wol_l, 0, part, kS, kH, kH, 8);
        splitk_epi_ln2_kernel<<<kS, 256, 0, stream>>>(part, bo_l, h, l1s_l, l1b_l, h1, h1_h, h1_l, 8);
        // FFN1: S=2 -> 384 blocks, gelu
        gemm64_pre<<<dim3(kF / 128, kS / 64, 2), 256, 0, stream>>>(
            h1_h, h1_l, w1h_l, w1l_l, 0, part, kS, kF, kH, 2);
        splitk_epi_sh_kernel<<<(int)(MN_F / 4 / 256), 256, 0, stream>>>(
            part, b1_l, ffn1_h, ffn1_l, MN_F, kF, 2, 1);
        // FFN2: S=8 -> 384 blocks; fused epi+bias+residual+LN
        gemm64_pre<<<dim3(kH / 128, kS / 64, 8), 256, 0, stream>>>(
            ffn1_h, ffn1_l, w2h_l, w2l_l, 0, part, kS, kH, kF, 8);
        splitk_epi_ln2_kernel<<<kS, 256, 0, stream>>>(part, b2_l, h1, l2s_l, l2b_l, h, hh_h, hh_l, 8);
    }

    // ---------- combine + classifier ----------
    combine_part_kernel<<<56, 256, 0, stream>>>(h, gp, ghv, cW, feat);
    cls_head_kernel<<<1, 256, 0, stream>>>(feat, cb, clsW, clsB, out);
}